// Round 10
// baseline (701.351 us; speedup 1.0000x reference)
//
#include <hip/hip_runtime.h>
#include <hip/hip_bf16.h>
#include <math.h>

constexpr int Bn  = 4;
constexpr int Nn  = 1024;
constexpr int Mmm = 1024;
constexpr int PFDc = 1024;
constexpr int ADc  = 256;
constexpr int GFDc = 512;
constexpr int Hc   = 4;
constexpr int NRc  = 16;
constexpr int NSPLIT = 32;
constexpr float COEFFc = -28.125f;    // -0.5/(CUT/(NR-1))^2
constexpr float SCALEc = 0.125f;      // DH^-0.5
constexpr float STEPc  = 2.0f / 15.0f;

__device__ __forceinline__ float addf(float a, float b) { return a + b; }
__device__ __forceinline__ double addd(double a, double b) { return a + b; }

#define BLK_REDUCE_F(OP, VAR, RES) \
  red[tid] = (VAR); __syncthreads(); \
  for (int st_ = 128; st_ > 0; st_ >>= 1) { if (tid < st_) red[tid] = OP(red[tid], red[tid + st_]); __syncthreads(); } \
  (RES) = red[0]; __syncthreads();

#define BLK_REDUCE_D(OP, VAR, RES) \
  redd[tid] = (VAR); __syncthreads(); \
  for (int st_ = 128; st_ > 0; st_ >>= 1) { if (tid < st_) redd[tid] = OP(redd[tid], redd[tid + st_]); __syncthreads(); } \
  (RES) = redd[0]; __syncthreads();

// ---------------------------------------------------------------------------
// 512-thread 128x128 double-buffered GEMM core, BK=8, 8 rows x 4 cols/thread.
// ---------------------------------------------------------------------------
__device__ __forceinline__ void g128core(
    const float* __restrict__ A, int lda, const float* __restrict__ W, int ldw,
    int kbeg, int kend, int r0, int c0, int tid,
    float As[2][8][132], float Ws[2][8][132], float acc[8][4])
{
  const int tx = tid & 31, ty = tid >> 5;   // tx 0..31, ty 0..15
  float ra[2], rb[2];
  #pragma unroll
  for (int j = 0; j < 2; ++j) {
    int e = tid + j * 512;
    ra[j] = A[(size_t)(r0 + (e >> 3)) * lda + kbeg + (e & 7)];
    rb[j] = W[(size_t)(kbeg + (e >> 7)) * ldw + c0 + (e & 127)];
  }
  #pragma unroll
  for (int j = 0; j < 2; ++j) {
    int e = tid + j * 512;
    As[0][e & 7][e >> 3] = ra[j];
    Ws[0][e >> 7][e & 127] = rb[j];
  }
  __syncthreads();

  const int nstep = (kend - kbeg) >> 3;
  for (int s = 0; s < nstep; ++s) {
    const int cur = s & 1;
    if (s + 1 < nstep) {
      const int k0 = kbeg + ((s + 1) << 3);
      #pragma unroll
      for (int j = 0; j < 2; ++j) {
        int e = tid + j * 512;
        ra[j] = A[(size_t)(r0 + (e >> 3)) * lda + k0 + (e & 7)];
        rb[j] = W[(size_t)(k0 + (e >> 7)) * ldw + c0 + (e & 127)];
      }
    }
    #pragma unroll
    for (int kk = 0; kk < 8; ++kk) {
      float4 a0 = *(const float4*)&As[cur][kk][ty * 4];
      float4 a1 = *(const float4*)&As[cur][kk][64 + ty * 4];
      float2 w0 = *(const float2*)&Ws[cur][kk][tx * 2];
      float2 w1 = *(const float2*)&Ws[cur][kk][64 + tx * 2];
      float a[8] = {a0.x, a0.y, a0.z, a0.w, a1.x, a1.y, a1.z, a1.w};
      float w[4] = {w0.x, w0.y, w1.x, w1.y};
      #pragma unroll
      for (int i = 0; i < 8; ++i)
        #pragma unroll
        for (int j = 0; j < 4; ++j)
          acc[i][j] = fmaf(a[i], w[j], acc[i][j]);
    }
    if (s + 1 < nstep) {
      #pragma unroll
      for (int j = 0; j < 2; ++j) {
        int e = tid + j * 512;
        As[cur ^ 1][e & 7][e >> 3] = ra[j];
        Ws[cur ^ 1][e >> 7][e & 127] = rb[j];
      }
    }
    __syncthreads();
  }
}

__device__ __forceinline__ int g128row(int i, int ty) { return (i < 4) ? ty * 4 + i : 64 + ty * 4 + (i - 4); }
__device__ __forceinline__ int g128col(int j, int tx) { return (j < 2) ? tx * 2 + j : 64 + tx * 2 + (j - 2); }

// Full-K 128x128 GEMM with bias/act epilogue (f1: K=256, Cc=1024).
__global__ __launch_bounds__(512) void gemm128_k(
    const float* __restrict__ A, const float* __restrict__ W, const float* __restrict__ bias,
    float* __restrict__ C, int K, int Cc, int act)
{
  __shared__ __align__(16) float As[2][8][132];
  __shared__ __align__(16) float Ws[2][8][132];
  const int tid = threadIdx.x;
  const int tx = tid & 31, ty = tid >> 5;
  const int r0 = blockIdx.y * 128, c0 = blockIdx.x * 128;
  float acc[8][4] = {};
  g128core(A, K, W, Cc, 0, K, r0, c0, tid, As, Ws, acc);
  #pragma unroll
  for (int i = 0; i < 8; ++i) {
    int r = r0 + g128row(i, ty);
    #pragma unroll
    for (int j = 0; j < 4; ++j) {
      int c = c0 + g128col(j, tx);
      float v = acc[i][j] + bias[c];
      if (act == 1) v = 0.5f * v * (1.f + erff(v * 0.70710678118654752f));
      C[(size_t)r * Cc + c] = v;
    }
  }
}

// Split-K=4 128x128 GEMM: 4096x256 output, K=1024. Raw partial -> P+z*1M.
__global__ __launch_bounds__(512) void gemm128sk_k(
    const float* __restrict__ A, const float* __restrict__ W, float* __restrict__ P)
{
  __shared__ __align__(16) float As[2][8][132];
  __shared__ __align__(16) float Ws[2][8][132];
  const int tid = threadIdx.x;
  const int tx = tid & 31, ty = tid >> 5;
  const int r0 = blockIdx.y * 128, c0 = blockIdx.x * 128;
  const int koff = blockIdx.z * 256;
  float acc[8][4] = {};
  g128core(A, 1024, W, 256, koff, koff + 256, r0, c0, tid, As, Ws, acc);
  float* Pz = P + (size_t)blockIdx.z * 1048576;
  #pragma unroll
  for (int i = 0; i < 8; ++i) {
    int r = r0 + g128row(i, ty);
    #pragma unroll
    for (int j = 0; j < 4; ++j)
      Pz[(size_t)r * 256 + c0 + g128col(j, tx)] = acc[i][j];
  }
}

// BOTH projection GEMMs in one launch: z<4 src, z>=4 tgt.
__global__ __launch_bounds__(512) void proj2sk_k(
    const float* __restrict__ srcf, const float* __restrict__ sfw,
    const float* __restrict__ tgtf, const float* __restrict__ tfw,
    float* __restrict__ Psrc, float* __restrict__ Ptgt)
{
  __shared__ __align__(16) float As[2][8][132];
  __shared__ __align__(16) float Ws[2][8][132];
  const int tid = threadIdx.x;
  const int tx = tid & 31, ty = tid >> 5;
  const int z = blockIdx.z;
  const float* A = (z < 4) ? srcf : tgtf;
  const float* W = (z < 4) ? sfw : tfw;
  float* P = ((z < 4) ? Psrc : Ptgt) + (size_t)(z & 3) * 1048576;
  const int r0 = blockIdx.y * 128, c0 = blockIdx.x * 128;
  const int koff = (z & 3) * 256;
  float acc[8][4] = {};
  g128core(A, 1024, W, 256, koff, koff + 256, r0, c0, tid, As, Ws, acc);
  #pragma unroll
  for (int i = 0; i < 8; ++i) {
    int r = r0 + g128row(i, ty);
    #pragma unroll
    for (int j = 0; j < 4; ++j)
      P[(size_t)r * 256 + c0 + g128col(j, tx)] = acc[i][j];
  }
}

// Batched NT 128x128 GEMM: logS[b][n][m] = (1/tau) sum_k A[b,n,k]*Bm[b,m,k].
__global__ __launch_bounds__(512) void gemm128nt_k(
    const float* __restrict__ A, const float* __restrict__ Bm, float* __restrict__ C,
    const float* __restrict__ temp)
{
  __shared__ __align__(16) float As[2][8][132];
  __shared__ __align__(16) float Bs[2][8][132];
  const int tid = threadIdx.x;
  const int tx = tid & 31, ty = tid >> 5;
  const int b = blockIdx.z;
  const int r0 = blockIdx.y * 128, c0 = blockIdx.x * 128;
  const float* Ab = A + (size_t)b * Nn * ADc;
  const float* Bb = Bm + (size_t)b * Mmm * ADc;
  float* Cb = C + (size_t)b * Nn * Mmm;
  float tau = fminf(fmaxf(temp[0], 0.01f), 1.0f);
  float inv_tau = 1.f / tau;
  float acc[8][4] = {};
  float ra[2], rb[2];
  #pragma unroll
  for (int j = 0; j < 2; ++j) {
    int e = tid + j * 512;
    ra[j] = Ab[(size_t)(r0 + (e >> 3)) * ADc + (e & 7)];
    rb[j] = Bb[(size_t)(c0 + (e >> 3)) * ADc + (e & 7)];
  }
  #pragma unroll
  for (int j = 0; j < 2; ++j) {
    int e = tid + j * 512;
    As[0][e & 7][e >> 3] = ra[j];
    Bs[0][e & 7][e >> 3] = rb[j];
  }
  __syncthreads();
  for (int s = 0; s < 32; ++s) {
    const int cur = s & 1;
    if (s + 1 < 32) {
      const int k0 = (s + 1) << 3;
      #pragma unroll
      for (int j = 0; j < 2; ++j) {
        int e = tid + j * 512;
        ra[j] = Ab[(size_t)(r0 + (e >> 3)) * ADc + k0 + (e & 7)];
        rb[j] = Bb[(size_t)(c0 + (e >> 3)) * ADc + k0 + (e & 7)];
      }
    }
    #pragma unroll
    for (int kk = 0; kk < 8; ++kk) {
      float4 a0 = *(const float4*)&As[cur][kk][ty * 4];
      float4 a1 = *(const float4*)&As[cur][kk][64 + ty * 4];
      float2 w0 = *(const float2*)&Bs[cur][kk][tx * 2];
      float2 w1 = *(const float2*)&Bs[cur][kk][64 + tx * 2];
      float a[8] = {a0.x, a0.y, a0.z, a0.w, a1.x, a1.y, a1.z, a1.w};
      float w[4] = {w0.x, w0.y, w1.x, w1.y};
      #pragma unroll
      for (int i = 0; i < 8; ++i)
        #pragma unroll
        for (int j = 0; j < 4; ++j)
          acc[i][j] = fmaf(a[i], w[j], acc[i][j]);
    }
    if (s + 1 < 32) {
      #pragma unroll
      for (int j = 0; j < 2; ++j) {
        int e = tid + j * 512;
        As[cur ^ 1][e & 7][e >> 3] = ra[j];
        Bs[cur ^ 1][e & 7][e >> 3] = rb[j];
      }
    }
    __syncthreads();
  }
  #pragma unroll
  for (int i = 0; i < 8; ++i) {
    int r = r0 + g128row(i, ty);
    #pragma unroll
    for (int j = 0; j < 4; ++j)
      Cb[(size_t)r * Mmm + c0 + g128col(j, tx)] = acc[i][j] * inv_tau;
  }
}

// ---------------------------------------------------------------------------
// Shared 512-thread 64x64 dbuf GEMM core (K=256 small-C GEMMs).
// ---------------------------------------------------------------------------
__device__ __forceinline__ void g512core(
    const float* __restrict__ A, int lda, const float* __restrict__ W, int ldw,
    int kbeg, int kend, int r0, int c0, int tid,
    float As[2][16][68], float Ws[2][16][68], float acc[2][4])
{
  const int tx = tid & 15, ty = tid >> 4;
  float ra[2], rb[2];
  #pragma unroll
  for (int j = 0; j < 2; ++j) {
    int e = tid + j * 512;
    ra[j] = A[(size_t)(r0 + (e >> 4)) * lda + kbeg + (e & 15)];
    rb[j] = W[(size_t)(kbeg + (e >> 6)) * ldw + c0 + (e & 63)];
  }
  #pragma unroll
  for (int j = 0; j < 2; ++j) {
    int e = tid + j * 512;
    As[0][e & 15][e >> 4] = ra[j];
    Ws[0][e >> 6][e & 63] = rb[j];
  }
  __syncthreads();

  const int nstep = (kend - kbeg) >> 4;
  for (int s = 0; s < nstep; ++s) {
    const int cur = s & 1;
    if (s + 1 < nstep) {
      const int k0 = kbeg + ((s + 1) << 4);
      #pragma unroll
      for (int j = 0; j < 2; ++j) {
        int e = tid + j * 512;
        ra[j] = A[(size_t)(r0 + (e >> 4)) * lda + k0 + (e & 15)];
        rb[j] = W[(size_t)(k0 + (e >> 6)) * ldw + c0 + (e & 63)];
      }
    }
    #pragma unroll
    for (int kk = 0; kk < 16; ++kk) {
      float2 av = *(const float2*)&As[cur][kk][ty * 2];
      float4 wv = *(const float4*)&Ws[cur][kk][tx * 4];
      float a[2] = {av.x, av.y};
      float w[4] = {wv.x, wv.y, wv.z, wv.w};
      #pragma unroll
      for (int i = 0; i < 2; ++i)
        #pragma unroll
        for (int j = 0; j < 4; ++j)
          acc[i][j] = fmaf(a[i], w[j], acc[i][j]);
    }
    if (s + 1 < nstep) {
      #pragma unroll
      for (int j = 0; j < 2; ++j) {
        int e = tid + j * 512;
        As[cur ^ 1][e & 15][e >> 4] = ra[j];
        Ws[cur ^ 1][e >> 6][e & 63] = rb[j];
      }
    }
    __syncthreads();
  }
}

// Full GEMM with bias/addsrc epilogue (out-proj).
__global__ __launch_bounds__(512) void gemm512_k(
    const float* __restrict__ A, const float* __restrict__ W, const float* __restrict__ bias,
    const float* __restrict__ addsrc, float* __restrict__ C,
    int K, int Cc, int act)
{
  __shared__ __align__(16) float As[2][16][68];
  __shared__ __align__(16) float Ws[2][16][68];
  const int tid = threadIdx.x;
  const int tx = tid & 15, ty = tid >> 4;
  const int r0 = blockIdx.y * 64, c0 = blockIdx.x * 64;
  float acc[2][4] = {};
  g512core(A, K, W, Cc, 0, K, r0, c0, tid, As, Ws, acc);
  #pragma unroll
  for (int i = 0; i < 2; ++i) {
    int r = r0 + ty * 2 + i;
    #pragma unroll
    for (int j = 0; j < 4; ++j) {
      int c = c0 + tx * 4 + j;
      float v = acc[i][j] + bias[c];
      if (addsrc) v += addsrc[(size_t)r * Cc + c];
      if (act == 1) v = 0.5f * v * (1.f + erff(v * 0.70710678118654752f));
      C[(size_t)r * Cc + c] = v;
    }
  }
}

// q + kv GEMMs in one launch: z=0 -> q; z=1,2 -> kv halves.
__global__ __launch_bounds__(512) void qkv_k(
    const float* __restrict__ xq, const float* __restrict__ qw, const float* __restrict__ qb,
    float* __restrict__ qout,
    const float* __restrict__ xc, const float* __restrict__ kvw, const float* __restrict__ kvb,
    float* __restrict__ kvout)
{
  __shared__ __align__(16) float As[2][16][68];
  __shared__ __align__(16) float Ws[2][16][68];
  const int tid = threadIdx.x;
  const int tx = tid & 15, ty = tid >> 4;
  const int z = blockIdx.z;
  const float* A = (z == 0) ? xq : xc;
  const float* W = (z == 0) ? qw : kvw;
  const float* bias = (z == 0) ? qb : kvb;
  float* C = (z == 0) ? qout : kvout;
  const int ldw = (z == 0) ? 256 : 512;
  const int coff = (z == 0) ? 0 : (z - 1) * 256;
  const int r0 = blockIdx.y * 64, c0 = blockIdx.x * 64 + coff;
  float acc[2][4] = {};
  g512core(A, 256, W, ldw, 0, 256, r0, c0, tid, As, Ws, acc);
  #pragma unroll
  for (int i = 0; i < 2; ++i) {
    int r = r0 + ty * 2 + i;
    #pragma unroll
    for (int j = 0; j < 4; ++j) {
      int c = c0 + tx * 4 + j;
      C[(size_t)r * ldw + c] = acc[i][j] + bias[c];
    }
  }
}

// Paired correspondence GEMMs (z=0: src_corr, z=1: tgt_corr), K=Cc=256.
__global__ __launch_bounds__(512) void gemm_corr2_k(
    const float* __restrict__ A0, const float* __restrict__ W0, const float* __restrict__ b0,
    float* __restrict__ C0,
    const float* __restrict__ A1, const float* __restrict__ W1, const float* __restrict__ b1,
    float* __restrict__ C1)
{
  __shared__ __align__(16) float As[2][16][68];
  __shared__ __align__(16) float Ws[2][16][68];
  const int tid = threadIdx.x;
  const int tx = tid & 15, ty = tid >> 4;
  const int r0 = blockIdx.y * 64, c0 = blockIdx.x * 64;
  const float* A = blockIdx.z ? A1 : A0;
  const float* W = blockIdx.z ? W1 : W0;
  const float* bias = blockIdx.z ? b1 : b0;
  float* C = blockIdx.z ? C1 : C0;
  float acc[2][4] = {};
  g512core(A, 256, W, 256, 0, 256, r0, c0, tid, As, Ws, acc);
  #pragma unroll
  for (int i = 0; i < 2; ++i) {
    int r = r0 + ty * 2 + i;
    #pragma unroll
    for (int j = 0; j < 4; ++j) {
      int c = c0 + tx * 4 + j;
      C[(size_t)r * 256 + c] = acc[i][j] + bias[c];
    }
  }
}

// ---------------------------------------------------------------------------
// Fused split-K reduce + bias + LN1+ReLU (proj) + LN2 (pre-attn), x2 streams.
// ---------------------------------------------------------------------------
__device__ __forceinline__ void ln4f_body(
    const float* __restrict__ p, const float* __restrict__ bias,
    const float* __restrict__ g, const float* __restrict__ bb,
    float* __restrict__ oproj, float* __restrict__ oln,
    const float* __restrict__ n1g, const float* __restrict__ n1b, int row, int tid)
{
  size_t o = (size_t)row * 256 + tid;
  float x = p[o] + p[o + 1048576] + p[o + 2097152] + p[o + 3145728] + bias[tid];
  __shared__ float as_[4], as2_[4];
  const int wv = tid >> 6, ln = tid & 63;
  // LN1 + ReLU
  float s = x, s2 = x * x;
  #pragma unroll
  for (int off = 32; off > 0; off >>= 1) {
    s  += __shfl_xor(s, off, 64);
    s2 += __shfl_xor(s2, off, 64);
  }
  if (ln == 0) { as_[wv] = s; as2_[wv] = s2; }
  __syncthreads();
  s  = as_[0] + as_[1] + as_[2] + as_[3];
  s2 = as2_[0] + as2_[1] + as2_[2] + as2_[3];
  float mu = s * (1.f / 256.f);
  float var = fmaxf(s2 * (1.f / 256.f) - mu * mu, 0.f);
  float inv = 1.f / sqrtf(var + 1e-5f);
  float v = fmaxf((x - mu) * inv * g[tid] + bb[tid], 0.f);
  oproj[o] = v;
  // LN2 (n1 params) on v
  float t = v, t2 = v * v;
  #pragma unroll
  for (int off = 32; off > 0; off >>= 1) {
    t  += __shfl_xor(t, off, 64);
    t2 += __shfl_xor(t2, off, 64);
  }
  __syncthreads();   // everyone done reading as_ before overwrite
  if (ln == 0) { as_[wv] = t; as2_[wv] = t2; }
  __syncthreads();
  t  = as_[0] + as_[1] + as_[2] + as_[3];
  t2 = as2_[0] + as2_[1] + as2_[2] + as2_[3];
  float mu2 = t * (1.f / 256.f);
  float var2 = fmaxf(t2 * (1.f / 256.f) - mu2 * mu2, 0.f);
  float inv2 = 1.f / sqrtf(var2 + 1e-5f);
  oln[o] = (v - mu2) * inv2 * n1g[tid] + n1b[tid];
}

__global__ __launch_bounds__(256) void ln4x2f_k(
    const float* __restrict__ p0, const float* __restrict__ b0,
    const float* __restrict__ g0, const float* __restrict__ bb0,
    float* __restrict__ o0, float* __restrict__ q0,
    const float* __restrict__ p1, const float* __restrict__ b1,
    const float* __restrict__ g1, const float* __restrict__ bb1,
    float* __restrict__ o1, float* __restrict__ q1,
    const float* __restrict__ n1g, const float* __restrict__ n1b)
{
  const int row = blockIdx.x;
  if (row < Bn * Nn) ln4f_body(p0, b0, g0, bb0, o0, q0, n1g, n1b, row, threadIdx.x);
  else               ln4f_body(p1, b1, g1, bb1, o1, q1, n1g, n1b, row - Bn * Nn, threadIdx.x);
}

// Split-K reduce + bias + residual accumulate (for f2): out += sum(p) + bias.
__global__ __launch_bounds__(256) void red4_k(
    const float* __restrict__ p, const float* __restrict__ bias, float* __restrict__ out)
{
  size_t i = (size_t)blockIdx.x * 256 + threadIdx.x;
  out[i] += p[i] + p[i + 1048576] + p[i + 2097152] + p[i + 3145728] + bias[threadIdx.x];
}

// Pack [kw|vw] (256x512) and [kb|vb] into contiguous buffers.
__global__ __launch_bounds__(256) void pack_kv_k(
    const float* __restrict__ kw, const float* __restrict__ kb,
    const float* __restrict__ vw, const float* __restrict__ vb,
    float* __restrict__ kvw, float* __restrict__ kvb)
{
  int i = blockIdx.x * 256 + threadIdx.x;
  if (i < 256 * 512) {
    int r = i >> 9, c = i & 511;
    kvw[i] = (c < 256) ? kw[r * 256 + c] : vw[r * 256 + (c - 256)];
  } else if (i < 256 * 512 + 512) {
    int c = i - 256 * 512;
    kvb[c] = (c < 256) ? kb[c] : vb[c - 256];
  }
}

// ---------------------------------------------------------------------------
// Fast LayerNorm for Cc=256 (pre-FFN h).
// ---------------------------------------------------------------------------
__global__ __launch_bounds__(256) void ln2_k(
    const float* __restrict__ in, const float* __restrict__ g, const float* __restrict__ bb,
    float* __restrict__ out, int relu)
{
  const int row = blockIdx.x;
  const int tid = threadIdx.x;
  float x = in[(size_t)row * 256 + tid];
  float s = x, s2 = x * x;
  #pragma unroll
  for (int off = 32; off > 0; off >>= 1) {
    s  += __shfl_xor(s, off, 64);
    s2 += __shfl_xor(s2, off, 64);
  }
  __shared__ float as_[4], as2_[4];
  const int wv = tid >> 6, ln = tid & 63;
  if (ln == 0) { as_[wv] = s; as2_[wv] = s2; }
  __syncthreads();
  s  = as_[0] + as_[1] + as_[2] + as_[3];
  s2 = as2_[0] + as2_[1] + as2_[2] + as2_[3];
  float mu = s * (1.f / 256.f);
  float var = fmaxf(s2 * (1.f / 256.f) - mu * mu, 0.f);
  float inv = 1.f / sqrtf(var + 1e-5f);
  float v = (x - mu) * inv * g[tid] + bb[tid];
  if (relu) v = fmaxf(v, 0.f);
  out[(size_t)row * 256 + tid] = v;
}

// ---------------------------------------------------------------------------
// Flash cross-attention, LDS diet for 3 blocks/CU:
//  - Tb 1024 entries (interp err ~7e-5 on logits)
//  - P kept in registers; PV reads P via __shfl from owning lane (same wave)
//  - Qs [64][34] (float2-aligned rows)
// LDS = 52,928 B -> 3 blocks/CU (3 waves/SIMD vs 2).
// ---------------------------------------------------------------------------
__global__ __launch_bounds__(256) void fattn(
    const float* __restrict__ q, const float* __restrict__ kv,
    const float* __restrict__ src_pts, const float* __restrict__ tgt_pts,
    const float* __restrict__ rbfw, float* __restrict__ ctx)
{
  const int bh = blockIdx.x;
  const int b = bh >> 2, h = bh & 3;
  const int n0 = blockIdx.y * 32;
  const int tid = threadIdx.x;
  const int tx = tid & 15, ty = tid >> 4;
  const int lane = tid & 63, w = tid >> 6;
  const int mml = lane >> 4;
  const int dd  = lane & 15;

  __shared__ __align__(16) float Qs[64][34];
  __shared__ __align__(16) float Ks[64][68];
  __shared__ __align__(16) float Vs[64][68];
  __shared__ float spx[32], spy[32], spz[32];
  __shared__ float tpx[64], tpy[64], tpz[64];
  __shared__ float rw[16];
  __shared__ __align__(8) float2 Tb[1024];

  if (tid < 16) rw[tid] = rbfw[tid * Hc + h];
  #pragma unroll
  for (int c = 0; c < 8; ++c) {
    int n = c * 4 + mml;
    int d = w * 16 + dd;
    Qs[d][n] = q[((size_t)b * Nn + n0 + n) * ADc + h * 64 + d];
  }
  if (tid < 32) {
    spx[tid] = src_pts[((size_t)b * Nn + n0 + tid) * 3 + 0];
    spy[tid] = src_pts[((size_t)b * Nn + n0 + tid) * 3 + 1];
    spz[tid] = src_pts[((size_t)b * Nn + n0 + tid) * 3 + 2];
  }
  __syncthreads();  // rw visible for table build

  // Build per-head bias table: 1024 entries over dist in [0,4].
  for (int i = tid; i < 1024; i += 256) {
    float di = (float)i * (1.0f / 256.0f);
    float s0 = 0.f, s1 = 0.f;
    #pragma unroll
    for (int r = 0; r < NRc; ++r) {
      float dq0 = di - STEPc * r;
      float dq1 = dq0 + (1.0f / 256.0f);
      s0 = fmaf(__expf(COEFFc * dq0 * dq0), rw[r], s0);
      s1 = fmaf(__expf(COEFFc * dq1 * dq1), rw[r], s1);
    }
    Tb[i] = make_float2(s0, s1 - s0);
  }

  float kreg[16], vreg[16];
  float tp0 = 0.f, tp1 = 0.f, tp2 = 0.f;
  {
    const size_t kb_ = ((size_t)b * Mmm) * 512 + h * 64;
    #pragma unroll
    for (int c = 0; c < 16; ++c) {
      kreg[c] = kv[kb_ + (size_t)(c * 4 + mml) * 512 + w * 16 + dd];
      vreg[c] = kv[kb_ + (size_t)(c * 4 + w) * 512 + 256 + lane];
    }
    if (tid < 64) {
      tp0 = tgt_pts[((size_t)b * Mmm + tid) * 3 + 0];
      tp1 = tgt_pts[((size_t)b * Mmm + tid) * 3 + 1];
      tp2 = tgt_pts[((size_t)b * Mmm + tid) * 3 + 2];
    }
  }

  float O[2][4] = {};
  float mrun[2] = {-1e30f, -1e30f};
  float lrun[2] = {0.f, 0.f};

  for (int t = 0; t < Mmm / 64; ++t) {
    __syncthreads();   // previous tile fully consumed (covers Tb/Qs at t=0)
    #pragma unroll
    for (int c = 0; c < 16; ++c) Ks[w * 16 + dd][c * 4 + mml] = kreg[c];
    #pragma unroll
    for (int c = 0; c < 16; ++c) Vs[c * 4 + w][lane] = vreg[c];
    if (tid < 64) { tpx[tid] = tp0; tpy[tid] = tp1; tpz[tid] = tp2; }
    if (t + 1 < Mmm / 64) {
      const size_t kb_ = ((size_t)b * Mmm + (t + 1) * 64) * 512 + h * 64;
      #pragma unroll
      for (int c = 0; c < 16; ++c) {
        kreg[c] = kv[kb_ + (size_t)(c * 4 + mml) * 512 + w * 16 + dd];
        vreg[c] = kv[kb_ + (size_t)(c * 4 + w) * 512 + 256 + lane];
      }
      if (tid < 64) {
        size_t tb_ = ((size_t)b * Mmm + (t + 1) * 64 + tid) * 3;
        tp0 = tgt_pts[tb_ + 0];
        tp1 = tgt_pts[tb_ + 1];
        tp2 = tgt_pts[tb_ + 2];
      }
    }
    __syncthreads();

    // QK^T
    float S[2][4] = {};
    #pragma unroll
    for (int d = 0; d < 64; ++d) {
      float2 qv = *(const float2*)&Qs[d][ty * 2];
      float4 kv4 = *(const float4*)&Ks[d][tx * 4];
      float kwv[4] = {kv4.x, kv4.y, kv4.z, kv4.w};
      #pragma unroll
      for (int j = 0; j < 4; ++j) {
        S[0][j] = fmaf(qv.x, kwv[j], S[0][j]);
        S[1][j] = fmaf(qv.y, kwv[j], S[1][j]);
      }
    }

    // geo bias + online softmax; P stays in registers (pv)
    float pv[2][4];
    #pragma unroll
    for (int i = 0; i < 2; ++i) {
      int n = ty * 2 + i;
      float s0 = spx[n], s1 = spy[n], s2 = spz[n];
      float sq = s0 * s0 + s1 * s1 + s2 * s2;
      float rmx = -1e30f;
      #pragma unroll
      for (int j = 0; j < 4; ++j) {
        int mj = tx * 4 + j;
        float t0 = tpx[mj], t1 = tpy[mj], t2 = tpz[mj];
        float d2 = sq + t0 * t0 + t1 * t1 + t2 * t2 - 2.f * (s0 * t0 + s1 * t1 + s2 * t2);
        float dist = sqrtf(fmaxf(d2, 0.f));
        float fidx = fminf(dist * 256.0f, 1023.0f);
        int i0 = (int)fidx;
        float frac = fidx - (float)i0;
        float2 tb = Tb[i0];
        float bias = fmaf(tb.y, frac, tb.x);
        float lv = S[i][j] * SCALEc + bias;
        S[i][j] = lv;
        rmx = fmaxf(rmx, lv);
      }
      #pragma unroll
      for (int off = 1; off < 16; off <<= 1)
        rmx = fmaxf(rmx, __shfl_xor(rmx, off, 64));
      float mn = fmaxf(mrun[i], rmx);
      float alpha = __expf(mrun[i] - mn);
      mrun[i] = mn;
      pv[i][0] = __expf(S[i][0] - mn);
      pv[i][1] = __expf(S[i][1] - mn);
      pv[i][2] = __expf(S[i][2] - mn);
      pv[i][3] = __expf(S[i][3] - mn);
      float rs = pv[i][0] + pv[i][1] + pv[i][2] + pv[i][3];
      #pragma unroll
      for (int off = 1; off < 16; off <<= 1)
        rs += __shfl_xor(rs, off, 64);
      lrun[i] = lrun[i] * alpha + rs;
      O[i][0] *= alpha; O[i][1] *= alpha; O[i][2] *= alpha; O[i][3] *= alpha;
    }

    // PV: P broadcast via shuffle from owning lane (same wave owns the row).
    #pragma unroll
    for (int m = 0; m < 64; ++m) {
      int src = (lane & 48) | (m >> 2);
      float pm0 = __shfl(pv[0][m & 3], src, 64);
      float pm1 = __shfl(pv[1][m & 3], src, 64);
      float4 vv = *(const float4*)&Vs[m][tx * 4];
      float vwv[4] = {vv.x, vv.y, vv.z, vv.w};
      #pragma unroll
      for (int j = 0; j < 4; ++j) {
        O[0][j] = fmaf(pm0, vwv[j], O[0][j]);
        O[1][j] = fmaf(pm1, vwv[j], O[1][j]);
      }
    }
  }

  #pragma unroll
  for (int i = 0; i < 2; ++i) {
    int n = n0 + ty * 2 + i;
    float invl = 1.f / lrun[i];
    size_t base = ((size_t)b * Nn + n) * ADc + h * 64 + tx * 4;
    ctx[base + 0] = O[i][0] * invl;
    ctx[base + 1] = O[i][1] * invl;
    ctx[base + 2] = O[i][2] * invl;
    ctx[base + 3] = O[i][3] * invl;
  }
}

// ---------------------------------------------------------------------------
// Sinkhorn, offset form: logS is READ-ONLY after the NT GEMM.
//   Rn = rowLSE(L0 - Cm); Cm = colLSE(L0 - Rn); (3x); S = exp(L0 - Rn - Cm)
// ---------------------------------------------------------------------------
__global__ __launch_bounds__(256) void row_lse3_k(
    const float* __restrict__ logS, const float* __restrict__ Cm, float* __restrict__ Rn)
{
  const int tid = threadIdx.x;
  const int bn = blockIdx.x;
  const int b = bn >> 10;
  const float* row = logS + (size_t)bn * Mmm;
  float4 v4 = *(const float4*)&row[tid * 4];
  if (Cm) {
    const float4 c4 = *(const float4*)&Cm[(size_t)b * Mmm + tid * 4];
    v4.x -= c4.x; v4.y -= c4.y; v4.z -= c4.z; v4.w -= c4.w;
  }
  float mx = fmaxf(fmaxf(v4.x, v4.y), fmaxf(v4.z, v4.w));
  float sm = __expf(v4.x - mx) + __expf(v4.y - mx) + __expf(v4.z - mx) + __expf(v4.w - mx);
  #pragma unroll
  for (int off = 32; off > 0; off >>= 1) {
    float mo = __shfl_xor(mx, off, 64);
    float so = __shfl_xor(sm, off, 64);
    float mn = fmaxf(mx, mo);
    sm = sm * __expf(mx - mn) + so * __expf(mo - mn);
    mx = mn;
  }
  __shared__ float wm[4], wsum[4];
  const int wv = tid >> 6, ln = tid & 63;
  if (ln == 0) { wm[wv] = mx; wsum[wv] = sm; }
  __syncthreads();
  if (tid == 0) {
    float m0 = fmaxf(fmaxf(wm[0], wm[1]), fmaxf(wm[2], wm[3]));
    float stot = wsum[0] * __expf(wm[0] - m0) + wsum[1] * __expf(wm[1] - m0)
               + wsum[2] * __expf(wm[2] - m0) + wsum[3] * __expf(wm[3] - m0);
    Rn[bn] = m0 + __logf(stot);
  }
}

__global__ __launch_bounds__(256) void col_part2_k(
    const float* __restrict__ logS, const float* __restrict__ Rn,
    float* __restrict__ pmax, float* __restrict__ psum)
{
  const int b = blockIdx.z, sp = blockIdx.y;
  const int m = blockIdx.x * 256 + threadIdx.x;
  const int RPS = Nn / NSPLIT;
  const float* base = logS + ((size_t)b * Nn + sp * RPS) * Mmm + m;
  const float* rn = Rn + (size_t)b * Nn + sp * RPS;
  float mx = -1e30f, sm = 0.f;
  for (int i = 0; i < RPS; ++i) {
    float v = base[(size_t)i * Mmm] - rn[i];
    if (v > mx) { sm = sm * __expf(mx - v) + 1.f; mx = v; }
    else sm += __expf(v - mx);
  }
  size_t o = ((size_t)b * NSPLIT + sp) * Mmm + m;
  pmax[o] = mx; psum[o] = sm;
}

__global__ __launch_bounds__(256) void col_comb_k(
    const float* __restrict__ pmax, const float* __restrict__ psum, float* __restrict__ colLse)
{
  const int b = blockIdx.y;
  const int m = blockIdx.x * 256 + threadIdx.x;
  float mx = -1e30f;
  for (int s = 0; s < NSPLIT; ++s) mx = fmaxf(mx, pmax[((size_t)b * NSPLIT + s) * Mmm + m]);
  float sm = 0.f;
  for (int s = 0; s < NSPLIT; ++s) {
    size_t o = ((size_t)b * NSPLIT + s) * Mmm + m;
    sm += psum[o] * __expf(pmax[o] - mx);
  }
  colLse[(size_t)b * Mmm + m] = mx + __logf(sm);
}

__global__ __launch_bounds__(256) void finalize2_k(
    const float* __restrict__ logS, const float* __restrict__ Rn, const float* __restrict__ Cm,
    const float* __restrict__ tgt_pts, float* __restrict__ outS, float* __restrict__ outConf,
    float* __restrict__ conf, float* __restrict__ tcp)
{
  const int tid = threadIdx.x;
  const int bn = blockIdx.x;
  const int b = bn >> 10;
  const float* row = logS + (size_t)bn * Mmm;
  const float rsub = Rn[bn];
  const float* cl = Cm + (size_t)b * Mmm;
  const float* tp = tgt_pts + (size_t)b * Mmm * 3;
  __shared__ float red[256];
  float mx = -1e30f, s0 = 0.f, s1 = 0.f, s2 = 0.f;
  for (int m = tid; m < Mmm; m += 256) {
    float sv = __expf(row[m] - rsub - cl[m]);
    outS[(size_t)bn * Mmm + m] = sv;
    mx = fmaxf(mx, sv);
    s0 = fmaf(sv, tp[m * 3 + 0], s0);
    s1 = fmaf(sv, tp[m * 3 + 1], s1);
    s2 = fmaf(sv, tp[m * 3 + 2], s2);
  }
  float rmx, r0, r1, r2;
  BLK_REDUCE_F(fmaxf, mx, rmx);
  BLK_REDUCE_F(addf, s0, r0);
  BLK_REDUCE_F(addf, s1, r1);
  BLK_REDUCE_F(addf, s2, r2);
  if (tid == 0) {
    conf[bn] = rmx;
    outConf[bn] = rmx;
    tcp[(size_t)bn * 3 + 0] = r0;
    tcp[(size_t)bn * 3 + 1] = r1;
    tcp[(size_t)bn * 3 + 2] = r2;
  }
}

// ---------------------------------------------------------------------------
// Kabsch: per-batch weighted sums + in-kernel SVD (thread 0). ONE launch.
// ---------------------------------------------------------------------------
__device__ __forceinline__ double trip(const double a[3], const double b[3], const double c[3]) {
  return a[0] * (b[1] * c[2] - b[2] * c[1])
       - a[1] * (b[0] * c[2] - b[2] * c[0])
       + a[2] * (b[0] * c[1] - b[1] * c[0]);
}

__device__ void kabsch_svd_dev(const double A[3][3], const double cs[3], const double ct[3],
                               int b, float* __restrict__ outR, float* __restrict__ outT)
{
  double Km[3][3];
  for (int i = 0; i < 3; ++i)
    for (int j = 0; j < 3; ++j)
      Km[i][j] = A[0][i] * A[0][j] + A[1][i] * A[1][j] + A[2][i] * A[2][j];
  double V[3][3] = {{1, 0, 0}, {0, 1, 0}, {0, 0, 1}};
  const int PP[3] = {0, 0, 1}, QQ[3] = {1, 2, 2};
  for (int sweep = 0; sweep < 30; ++sweep) {
    for (int pi = 0; pi < 3; ++pi) {
      int p = PP[pi], qd = QQ[pi];
      double apq = Km[p][qd];
      if (fabs(apq) < 1e-300) continue;
      double theta = (Km[qd][qd] - Km[p][p]) / (2.0 * apq);
      double tt = (theta >= 0 ? 1.0 : -1.0) / (fabs(theta) + sqrt(theta * theta + 1.0));
      double cc = 1.0 / sqrt(tt * tt + 1.0), ss = tt * cc;
      for (int r = 0; r < 3; ++r) {
        double kp = Km[r][p], kq = Km[r][qd];
        Km[r][p] = cc * kp - ss * kq; Km[r][qd] = ss * kp + cc * kq;
      }
      for (int c = 0; c < 3; ++c) {
        double kp = Km[p][c], kq = Km[qd][c];
        Km[p][c] = cc * kp - ss * kq; Km[qd][c] = ss * kp + cc * kq;
      }
      for (int r = 0; r < 3; ++r) {
        double vp = V[r][p], vq = V[r][qd];
        V[r][p] = cc * vp - ss * vq; V[r][qd] = ss * vp + cc * vq;
      }
    }
  }
  double lam[3] = {Km[0][0], Km[1][1], Km[2][2]};
  int i0 = 0, i1 = 1, i2 = 2, tsw;
  if (lam[i0] < lam[i1]) { tsw = i0; i0 = i1; i1 = tsw; }
  if (lam[i0] < lam[i2]) { tsw = i0; i0 = i2; i2 = tsw; }
  if (lam[i1] < lam[i2]) { tsw = i1; i1 = i2; i2 = tsw; }
  double vv[3][3];
  for (int r = 0; r < 3; ++r) { vv[0][r] = V[r][i0]; vv[1][r] = V[r][i1]; vv[2][r] = V[r][i2]; }
  double sg[3] = { sqrt(fmax(lam[i0], 0.0)), sqrt(fmax(lam[i1], 0.0)), sqrt(fmax(lam[i2], 0.0)) };

  double uu[3][3];
  double eps = 1e-12 * (sg[0] > 0 ? sg[0] : 1.0);
  if (sg[0] > eps) {
    for (int r = 0; r < 3; ++r)
      uu[0][r] = (A[r][0] * vv[0][0] + A[r][1] * vv[0][1] + A[r][2] * vv[0][2]) / sg[0];
    double n = sqrt(uu[0][0]*uu[0][0] + uu[0][1]*uu[0][1] + uu[0][2]*uu[0][2]);
    if (n > 1e-14) { uu[0][0]/=n; uu[0][1]/=n; uu[0][2]/=n; }
  } else { uu[0][0]=1; uu[0][1]=0; uu[0][2]=0; }
  if (sg[1] > eps) {
    for (int r = 0; r < 3; ++r)
      uu[1][r] = (A[r][0] * vv[1][0] + A[r][1] * vv[1][1] + A[r][2] * vv[1][2]) / sg[1];
  } else {
    int ax = (fabs(uu[0][0]) <= fabs(uu[0][1]) && fabs(uu[0][0]) <= fabs(uu[0][2])) ? 0
           : (fabs(uu[0][1]) <= fabs(uu[0][2]) ? 1 : 2);
    uu[1][0] = uu[1][1] = uu[1][2] = 0.0; uu[1][ax] = 1.0;
  }
  {
    double pr = uu[0][0]*uu[1][0] + uu[0][1]*uu[1][1] + uu[0][2]*uu[1][2];
    for (int r = 0; r < 3; ++r) uu[1][r] -= pr * uu[0][r];
    double n = sqrt(uu[1][0]*uu[1][0] + uu[1][1]*uu[1][1] + uu[1][2]*uu[1][2]);
    if (n > 1e-14) { uu[1][0]/=n; uu[1][1]/=n; uu[1][2]/=n; }
  }
  if (sg[2] > eps) {
    for (int r = 0; r < 3; ++r)
      uu[2][r] = (A[r][0] * vv[2][0] + A[r][1] * vv[2][1] + A[r][2] * vv[2][2]) / sg[2];
    double p0 = uu[0][0]*uu[2][0] + uu[0][1]*uu[2][1] + uu[0][2]*uu[2][2];
    double p1 = uu[1][0]*uu[2][0] + uu[1][1]*uu[2][1] + uu[1][2]*uu[2][2];
    for (int r = 0; r < 3; ++r) uu[2][r] -= p0 * uu[0][r] + p1 * uu[1][r];
    double n = sqrt(uu[2][0]*uu[2][0] + uu[2][1]*uu[2][1] + uu[2][2]*uu[2][2]);
    if (n > 1e-14) { uu[2][0]/=n; uu[2][1]/=n; uu[2][2]/=n; }
    else {
      uu[2][0] = uu[0][1]*uu[1][2] - uu[0][2]*uu[1][1];
      uu[2][1] = uu[0][2]*uu[1][0] - uu[0][0]*uu[1][2];
      uu[2][2] = uu[0][0]*uu[1][1] - uu[0][1]*uu[1][0];
    }
  } else {
    uu[2][0] = uu[0][1]*uu[1][2] - uu[0][2]*uu[1][1];
    uu[2][1] = uu[0][2]*uu[1][0] - uu[0][0]*uu[1][2];
    uu[2][2] = uu[0][0]*uu[1][1] - uu[0][1]*uu[1][0];
  }

  double detU = trip(uu[0], uu[1], uu[2]);
  double detV = trip(vv[0], vv[1], vv[2]);
  double d = (detU * detV < 0.0) ? -1.0 : 1.0;

  double R[3][3];
  for (int i = 0; i < 3; ++i)
    for (int j = 0; j < 3; ++j)
      R[i][j] = vv[0][i] * uu[0][j] + vv[1][i] * uu[1][j] + d * vv[2][i] * uu[2][j];
  for (int i = 0; i < 3; ++i) {
    double t = ct[i] - (R[i][0] * cs[0] + R[i][1] * cs[1] + R[i][2] * cs[2]);
    outT[(size_t)b * 3 + i] = (float)t;
    for (int j = 0; j < 3; ++j)
      outR[(size_t)b * 9 + i * 3 + j] = (float)R[i][j];
  }
}

__global__ __launch_bounds__(256) void kabsch_k(
    const float* __restrict__ conf, const float* __restrict__ src_pts,
    const float* __restrict__ tcp, float* __restrict__ outR, float* __restrict__ outT)
{
  const int b = blockIdx.x;
  const int tid = threadIdx.x;
  __shared__ double redd[256];
  __shared__ double sh[6];
  __shared__ double shk[9];
  const float* cb = conf + (size_t)b * Nn;
  const float* sb = src_pts + (size_t)b * Nn * 3;
  const float* tb = tcp + (size_t)b * Nn * 3;

  double a = 0.0;
  for (int n = tid; n < Nn; n += 256) a += (double)cb[n];
  double wsum; BLK_REDUCE_D(addd, a, wsum);
  double inv = 1.0 / (wsum + 1e-8);

  double c0 = 0, c1 = 0, c2 = 0, t0 = 0, t1 = 0, t2 = 0;
  for (int n = tid; n < Nn; n += 256) {
    double wn = (double)cb[n] * inv;
    c0 += wn * (double)sb[n * 3 + 0];
    c1 += wn * (double)sb[n * 3 + 1];
    c2 += wn * (double)sb[n * 3 + 2];
    t0 += wn * (double)tb[n * 3 + 0];
    t1 += wn * (double)tb[n * 3 + 1];
    t2 += wn * (double)tb[n * 3 + 2];
  }
  double r;
  BLK_REDUCE_D(addd, c0, r); if (tid == 0) sh[0] = r; __syncthreads();
  BLK_REDUCE_D(addd, c1, r); if (tid == 0) sh[1] = r; __syncthreads();
  BLK_REDUCE_D(addd, c2, r); if (tid == 0) sh[2] = r; __syncthreads();
  BLK_REDUCE_D(addd, t0, r); if (tid == 0) sh[3] = r; __syncthreads();
  BLK_REDUCE_D(addd, t1, r); if (tid == 0) sh[4] = r; __syncthreads();
  BLK_REDUCE_D(addd, t2, r); if (tid == 0) sh[5] = r; __syncthreads();
  double cs[3] = {sh[0], sh[1], sh[2]};
  double ct[3] = {sh[3], sh[4], sh[5]};

  double hm[9] = {};
  for (int n = tid; n < Nn; n += 256) {
    double wn = (double)cb[n] * inv;
    double d0 = (double)sb[n * 3 + 0] - cs[0];
    double d1 = (double)sb[n * 3 + 1] - cs[1];
    double d2 = (double)sb[n * 3 + 2] - cs[2];
    double e0 = (double)tb[n * 3 + 0] - ct[0];
    double e1 = (double)tb[n * 3 + 1] - ct[1];
    double e2 = (double)tb[n * 3 + 2] - ct[2];
    hm[0] += wn * d0 * e0; hm[1] += wn * d0 * e1; hm[2] += wn * d0 * e2;
    hm[3] += wn * d1 * e0; hm[4] += wn * d1 * e1; hm[5] += wn * d1 * e2;
    hm[6] += wn * d2 * e0; hm[7] += wn * d2 * e1; hm[8] += wn * d2 * e2;
  }
  for (int i = 0; i < 9; ++i) {
    BLK_REDUCE_D(addd, hm[i], r);
    if (tid == 0) shk[i] = r;
    __syncthreads();
  }
  if (tid == 0) {
    double A[3][3];
    for (int i = 0; i < 3; ++i)
      for (int j = 0; j < 3; ++j) A[i][j] = shk[i * 3 + j];
    kabsch_svd_dev(A, cs, ct, b, outR, outT);
  }
}

// x.max over N: partials over 64-row chunks (grid (B,16))
__global__ __launch_bounds__(256) void xmax_part_k(const float* __restrict__ x, float* __restrict__ part)
{
  const int b = blockIdx.x, ch = blockIdx.y;
  const int d = threadIdx.x;
  float mx = -1e30f;
  const int n0 = ch * 64;
  for (int n = n0; n < n0 + 64; ++n)
    mx = fmaxf(mx, x[((size_t)b * Nn + n) * ADc + d]);
  part[((size_t)b * 16 + ch) * ADc + d] = mx;
}

// Fused pool head: combine partials -> proj (256->512) -> LN -> ReLU -> concat.
__global__ __launch_bounds__(256) void pool_k(
    const float* __restrict__ part, const float* __restrict__ gp_w, const float* __restrict__ gp_b,
    const float* __restrict__ gp_g, const float* __restrict__ gp_bb,
    const float* __restrict__ tgt_glob, float* __restrict__ outC)
{
  const int b = blockIdx.x;
  const int tid = threadIdx.x;
  __shared__ float xm[256];
  float mx = -1e30f;
  #pragma unroll
  for (int c = 0; c < 16; ++c)
    mx = fmaxf(mx, part[((size_t)b * 16 + c) * 256 + tid]);
  xm[tid] = mx;
  __syncthreads();

  float acc0 = gp_b[tid], acc1 = gp_b[tid + 256];
  for (int k = 0; k < 256; ++k) {
    float xv = xm[k];
    acc0 = fmaf(xv, gp_w[(size_t)k * 512 + tid], acc0);
    acc1 = fmaf(xv, gp_w[(size_t)k * 512 + 256 + tid], acc1);
  }
  // LN over 512
  float s = acc0 + acc1, s2 = acc0 * acc0 + acc1 * acc1;
  #pragma unroll
  for (int off = 32; off > 0; off >>= 1) {
    s  += __shfl_xor(s, off, 64);
    s2 += __shfl_xor(s2, off, 64);
  }
  __shared__ float aw[4], aw2[4];
  const int wv = tid >> 6, ln = tid & 63;
  if (ln == 0) { aw[wv] = s; aw2[wv] = s2; }
  __syncthreads();
  s  = aw[0] + aw[1] + aw[2] + aw[3];
  s2 = aw2[0] + aw2[1] + aw2[2] + aw2[3];
  float mu = s * (1.f / 512.f);
  float var = fmaxf(s2 * (1.f / 512.f) - mu * mu, 0.f);
  float inv = 1.f / sqrtf(var + 1e-5f);
  float v0 = fmaxf((acc0 - mu) * inv * gp_g[tid] + gp_bb[tid], 0.f);
  float v1 = fmaxf((acc1 - mu) * inv * gp_g[tid + 256] + gp_bb[tid + 256], 0.f);
  size_t ob = (size_t)b * 1024;
  outC[ob + tid] = v0;
  outC[ob + 256 + tid] = v1;
  outC[ob + 512 + tid] = tgt_glob[(size_t)b * 512 + tid];
  outC[ob + 768 + tid] = tgt_glob[(size_t)b * 512 + 256 + tid];
}

// ---------------------------------------------------------------------------
extern "C" void kernel_launch(void* const* d_in, const int* in_sizes, int n_in,
                              void* d_out, int out_size, void* d_ws, size_t ws_size,
                              hipStream_t stream) {
  (void)in_sizes; (void)n_in; (void)out_size; (void)ws_size;
  const float* src_feats = (const float*)d_in[0];
  const float* tgt_feats = (const float*)d_in[1];
  const float* src_pts   = (const float*)d_in[2];
  const float* tgt_pts   = (const float*)d_in[3];
  const float* tgt_glob  = (const float*)d_in[4];
  const float* sfp_w = (const float*)d_in[5];  const float* sfp_b = (const float*)d_in[6];
  const float* sfp_g = (const float*)d_in[7];  const float* sfp_bb = (const float*)d_in[8];
  const float* tfp_w = (const float*)d_in[9];  const float* tfp_b = (const float*)d_in[10];
  const float* tfp_g = (const float*)d_in[11]; const float* tfp_bb = (const float*)d_in[12];
  const float* rbf_w = (const float*)d_in[13];
  const float* qw = (const float*)d_in[14]; const float* qb = (const float*)d_in[15];
  const float* kw = (const float*)d_in[16]; const float* kb = (const float*)d_in[17];
  const float* vw = (const float*)d_in[18]; const float* vb = (const float*)d_in[19];
  const float* ow = (const float*)d_in[20]; const float* ob = (const float*)d_in[21];
  const float* n1_g = (const float*)d_in[22]; const float* n1_b = (const float*)d_in[23];
  const float* f1_w = (const float*)d_in[24]; const float* f1_b = (const float*)d_in[25];
  const float* f2_w = (const float*)d_in[26]; const float* f2_b = (const float*)d_in[27];
  const float* n2_g = (const float*)d_in[28]; const float* n2_b = (const float*)d_in[29];
  const float* scp_w = (const float*)d_in[30]; const float* scp_b = (const float*)d_in[31];
  const float* tcp_w = (const float*)d_in[32]; const float* tcp_b = (const float*)d_in[33];
  const float* temp  = (const float*)d_in[34];
  const float* gp_w = (const float*)d_in[35]; const float* gp_b = (const float*)d_in[36];
  const float* gp_g = (const float*)d_in[37]; const float* gp_bb = (const float*)d_in[38];

  float* out = (float*)d_out;
  float* outR    = out;                    // (B,3,3)
  float* outT    = out + 36;               // (B,3)
  float* outC    = out + 48;               // (B,1024)
  float* outConf = out + 48 + 4096;        // (B,N)
  float* outS    = out + 48 + 4096 + 4096; // (B,N,M) -- split-K / tgt_corr scratch

  float* ws = (float*)d_ws;
  const size_t M1 = 1048576;
  float* A_   = ws + 0 * M1;
  float* B_   = ws + 1 * M1;
  float* C_   = ws + 2 * M1;
  float* D_   = ws + 3 * M1;   // kv packed output spans D..E (8MB)
  float* E_   = ws + 4 * M1;
  float* F_   = ws + 5 * M1;
  float* G_   = ws + 6 * M1;
  float* logS = ws + 0 * M1;     // slots 0..3
  float* hid  = ws + 1 * M1;     // slots 1..4
  float* tail = ws + 7 * M1;
  float* colLse = tail;                         // 4096
  float* pmax   = colLse + 4096;                // 131072 (also kvw pack)
  float* psum   = pmax + 131072;                // 131072 (also kvb pack)
  float* conf   = psum + 131072;                // 4096
  float* tcp    = conf + 4096;                  // 12288
  float* xmax   = tcp + 12288;                  // 1024 (layout keep)
  float* glraw  = xmax + 1024;                  // 2048 (layout keep)
  float* gl     = glraw + 2048;                 // 2048 (layout keep)
  double* kab   = (double*)(gl + 2048);         // 128 floats (layout keep)
  float* xpart  = (float*)(kab + 64);           // 16384 floats
  float* Rn     = xpart + 16384;                // 4096 (Sinkhorn row offsets)
  float* kvw    = pmax;                         // 131072 floats = 256x512
  float* kvb    = psum;                         // 512 floats

  const int BN = Bn * Nn;   // 4096

  // 0) pack [kw|vw] weights (dead Sinkhorn buffers; consumed before Sinkhorn)
  pack_kv_k<<<514, 256, 0, stream>>>(kw, kb, vw, vb, kvw, kvb);

  // 1) BOTH projections in one split-K launch; fused reduce+LN+ReLU+preLN
  proj2sk_k<<<dim3(2, 32, 8), 512, 0, stream>>>(src_feats, sfp_w, tgt_feats, tfp_w, outS, hid);
  ln4x2f_k<<<2 * BN, 256, 0, stream>>>(outS, sfp_b, sfp_g, sfp_bb, G_, A_,
                                       hid, tfp_b, tfp_g, tfp_bb, F_, B_,
                                       n1_g, n1_b);   // G=src_proj, A=xq, F=tgt_proj, B=xc

  // 2) q + kv in one launch
  qkv_k<<<dim3(4, 64, 3), 512, 0, stream>>>(A_, qw, qb, C_, B_, kvw, kvb, D_);

  // 3) flash attention, out-proj + residual
  fattn<<<dim3(Bn * Hc, Nn / 32), 256, 0, stream>>>(C_, D_, src_pts, tgt_pts, rbf_w, B_);  // ctx -> B
  gemm512_k<<<dim3(4, 64), 512, 0, stream>>>(B_, ow, ob, G_, G_, ADc, ADc, 0);

  // 4) FFN
  ln2_k<<<BN, 256, 0, stream>>>(G_, n2_g, n2_b, A_, 0);                       // h -> A
  gemm128_k<<<dim3(8, 32), 512, 0, stream>>>(A_, f1_w, f1_b, hid, ADc, 1024, 1);
  gemm128sk_k<<<dim3(2, 32, 4), 512, 0, stream>>>(hid, f2_w, outS);
  red4_k<<<BN, 256, 0, stream>>>(outS, f2_b, G_);                             // x += ffn

  // 5) correspondences (paired): src_corr -> E, tgt_corr -> outS
  gemm_corr2_k<<<dim3(4, 64, 2), 512, 0, stream>>>(G_, scp_w, scp_b, E_,
                                                   F_, tcp_w, tcp_b, outS);
  gemm128nt_k<<<dim3(8, 8, Bn), 512, 0, stream>>>(E_, outS, logS, temp);

  // 6) Sinkhorn (offset form, logS read-only) + finalize
  for (int it = 0; it < 3; ++it) {
    row_lse3_k<<<BN, 256, 0, stream>>>(logS, it == 0 ? nullptr : colLse, Rn);
    col_part2_k<<<dim3(Mmm / 256, NSPLIT, Bn), 256, 0, stream>>>(logS, Rn, pmax, psum);
    col_comb_k<<<dim3(Mmm / 256, Bn), 256, 0, stream>>>(pmax, psum, colLse);
  }
  finalize2_k<<<BN, 256, 0, stream>>>(logS, Rn, colLse, tgt_pts, outS, outConf, conf, tcp);

  // 7) Kabsch (reduce + SVD in one kernel)
  kabsch_k<<<Bn, 256, 0, stream>>>(conf, src_pts, tcp, outR, outT);

  // 8) global pooling head (G intact): partials + fused tail
  xmax_part_k<<<dim3(Bn, 16), 256, 0, stream>>>(G_, xpart);
  pool_k<<<Bn, 256, 0, stream>>>(xpart, gp_w, gp_b, gp_g, gp_bb, tgt_glob, outC);
}

// Round 12
// 672.408 us; speedup vs baseline: 1.0430x; 1.0430x over previous
//
#include <hip/hip_runtime.h>
#include <hip/hip_bf16.h>
#include <math.h>

constexpr int Bn  = 4;
constexpr int Nn  = 1024;
constexpr int Mmm = 1024;
constexpr int PFDc = 1024;
constexpr int ADc  = 256;
constexpr int GFDc = 512;
constexpr int Hc   = 4;
constexpr int NRc  = 16;
constexpr int NSPLIT = 32;
constexpr float COEFFc = -28.125f;    // -0.5/(CUT/(NR-1))^2
constexpr float SCALEc = 0.125f;      // DH^-0.5
constexpr float STEPc  = 2.0f / 15.0f;

__device__ __forceinline__ float addf(float a, float b) { return a + b; }
__device__ __forceinline__ double addd(double a, double b) { return a + b; }

#define BLK_REDUCE_F(OP, VAR, RES) \
  red[tid] = (VAR); __syncthreads(); \
  for (int st_ = 128; st_ > 0; st_ >>= 1) { if (tid < st_) red[tid] = OP(red[tid], red[tid + st_]); __syncthreads(); } \
  (RES) = red[0]; __syncthreads();

#define BLK_REDUCE_D(OP, VAR, RES) \
  redd[tid] = (VAR); __syncthreads(); \
  for (int st_ = 128; st_ > 0; st_ >>= 1) { if (tid < st_) redd[tid] = OP(redd[tid], redd[tid + st_]); __syncthreads(); } \
  (RES) = redd[0]; __syncthreads();

// ---------------------------------------------------------------------------
// 512-thread 128x128 double-buffered GEMM core, BK=8, 8 rows x 4 cols/thread.
// ---------------------------------------------------------------------------
__device__ __forceinline__ void g128core(
    const float* __restrict__ A, int lda, const float* __restrict__ W, int ldw,
    int kbeg, int kend, int r0, int c0, int tid,
    float As[2][8][132], float Ws[2][8][132], float acc[8][4])
{
  const int tx = tid & 31, ty = tid >> 5;   // tx 0..31, ty 0..15
  float ra[2], rb[2];
  #pragma unroll
  for (int j = 0; j < 2; ++j) {
    int e = tid + j * 512;
    ra[j] = A[(size_t)(r0 + (e >> 3)) * lda + kbeg + (e & 7)];
    rb[j] = W[(size_t)(kbeg + (e >> 7)) * ldw + c0 + (e & 127)];
  }
  #pragma unroll
  for (int j = 0; j < 2; ++j) {
    int e = tid + j * 512;
    As[0][e & 7][e >> 3] = ra[j];
    Ws[0][e >> 7][e & 127] = rb[j];
  }
  __syncthreads();

  const int nstep = (kend - kbeg) >> 3;
  for (int s = 0; s < nstep; ++s) {
    const int cur = s & 1;
    if (s + 1 < nstep) {
      const int k0 = kbeg + ((s + 1) << 3);
      #pragma unroll
      for (int j = 0; j < 2; ++j) {
        int e = tid + j * 512;
        ra[j] = A[(size_t)(r0 + (e >> 3)) * lda + k0 + (e & 7)];
        rb[j] = W[(size_t)(k0 + (e >> 7)) * ldw + c0 + (e & 127)];
      }
    }
    #pragma unroll
    for (int kk = 0; kk < 8; ++kk) {
      float4 a0 = *(const float4*)&As[cur][kk][ty * 4];
      float4 a1 = *(const float4*)&As[cur][kk][64 + ty * 4];
      float2 w0 = *(const float2*)&Ws[cur][kk][tx * 2];
      float2 w1 = *(const float2*)&Ws[cur][kk][64 + tx * 2];
      float a[8] = {a0.x, a0.y, a0.z, a0.w, a1.x, a1.y, a1.z, a1.w};
      float w[4] = {w0.x, w0.y, w1.x, w1.y};
      #pragma unroll
      for (int i = 0; i < 8; ++i)
        #pragma unroll
        for (int j = 0; j < 4; ++j)
          acc[i][j] = fmaf(a[i], w[j], acc[i][j]);
    }
    if (s + 1 < nstep) {
      #pragma unroll
      for (int j = 0; j < 2; ++j) {
        int e = tid + j * 512;
        As[cur ^ 1][e & 7][e >> 3] = ra[j];
        Ws[cur ^ 1][e >> 7][e & 127] = rb[j];
      }
    }
    __syncthreads();
  }
}

__device__ __forceinline__ int g128row(int i, int ty) { return (i < 4) ? ty * 4 + i : 64 + ty * 4 + (i - 4); }
__device__ __forceinline__ int g128col(int j, int tx) { return (j < 2) ? tx * 2 + j : 64 + tx * 2 + (j - 2); }

// Full-K 128x128 GEMM with bias/act epilogue (f1: K=256, Cc=1024).
__global__ __launch_bounds__(512) void gemm128_k(
    const float* __restrict__ A, const float* __restrict__ W, const float* __restrict__ bias,
    float* __restrict__ C, int K, int Cc, int act)
{
  __shared__ __align__(16) float As[2][8][132];
  __shared__ __align__(16) float Ws[2][8][132];
  const int tid = threadIdx.x;
  const int tx = tid & 31, ty = tid >> 5;
  const int r0 = blockIdx.y * 128, c0 = blockIdx.x * 128;
  float acc[8][4] = {};
  g128core(A, K, W, Cc, 0, K, r0, c0, tid, As, Ws, acc);
  #pragma unroll
  for (int i = 0; i < 8; ++i) {
    int r = r0 + g128row(i, ty);
    #pragma unroll
    for (int j = 0; j < 4; ++j) {
      int c = c0 + g128col(j, tx);
      float v = acc[i][j] + bias[c];
      if (act == 1) v = 0.5f * v * (1.f + erff(v * 0.70710678118654752f));
      C[(size_t)r * Cc + c] = v;
    }
  }
}

// Split-K=4 128x128 GEMM: 4096x256 output, K=1024. Raw partial -> P+z*1M.
__global__ __launch_bounds__(512) void gemm128sk_k(
    const float* __restrict__ A, const float* __restrict__ W, float* __restrict__ P)
{
  __shared__ __align__(16) float As[2][8][132];
  __shared__ __align__(16) float Ws[2][8][132];
  const int tid = threadIdx.x;
  const int tx = tid & 31, ty = tid >> 5;
  const int r0 = blockIdx.y * 128, c0 = blockIdx.x * 128;
  const int koff = blockIdx.z * 256;
  float acc[8][4] = {};
  g128core(A, 1024, W, 256, koff, koff + 256, r0, c0, tid, As, Ws, acc);
  float* Pz = P + (size_t)blockIdx.z * 1048576;
  #pragma unroll
  for (int i = 0; i < 8; ++i) {
    int r = r0 + g128row(i, ty);
    #pragma unroll
    for (int j = 0; j < 4; ++j)
      Pz[(size_t)r * 256 + c0 + g128col(j, tx)] = acc[i][j];
  }
}

// BOTH projection GEMMs in one launch: z<4 src, z>=4 tgt.
__global__ __launch_bounds__(512) void proj2sk_k(
    const float* __restrict__ srcf, const float* __restrict__ sfw,
    const float* __restrict__ tgtf, const float* __restrict__ tfw,
    float* __restrict__ Psrc, float* __restrict__ Ptgt)
{
  __shared__ __align__(16) float As[2][8][132];
  __shared__ __align__(16) float Ws[2][8][132];
  const int tid = threadIdx.x;
  const int tx = tid & 31, ty = tid >> 5;
  const int z = blockIdx.z;
  const float* A = (z < 4) ? srcf : tgtf;
  const float* W = (z < 4) ? sfw : tfw;
  float* P = ((z < 4) ? Psrc : Ptgt) + (size_t)(z & 3) * 1048576;
  const int r0 = blockIdx.y * 128, c0 = blockIdx.x * 128;
  const int koff = (z & 3) * 256;
  float acc[8][4] = {};
  g128core(A, 1024, W, 256, koff, koff + 256, r0, c0, tid, As, Ws, acc);
  #pragma unroll
  for (int i = 0; i < 8; ++i) {
    int r = r0 + g128row(i, ty);
    #pragma unroll
    for (int j = 0; j < 4; ++j)
      P[(size_t)r * 256 + c0 + g128col(j, tx)] = acc[i][j];
  }
}

// Batched NT 128x128 GEMM: logS[b][n][m] = (1/tau) sum_k A[b,n,k]*Bm[b,m,k].
__global__ __launch_bounds__(512) void gemm128nt_k(
    const float* __restrict__ A, const float* __restrict__ Bm, float* __restrict__ C,
    const float* __restrict__ temp)
{
  __shared__ __align__(16) float As[2][8][132];
  __shared__ __align__(16) float Bs[2][8][132];
  const int tid = threadIdx.x;
  const int tx = tid & 31, ty = tid >> 5;
  const int b = blockIdx.z;
  const int r0 = blockIdx.y * 128, c0 = blockIdx.x * 128;
  const float* Ab = A + (size_t)b * Nn * ADc;
  const float* Bb = Bm + (size_t)b * Mmm * ADc;
  float* Cb = C + (size_t)b * Nn * Mmm;
  float tau = fminf(fmaxf(temp[0], 0.01f), 1.0f);
  float inv_tau = 1.f / tau;
  float acc[8][4] = {};
  float ra[2], rb[2];
  #pragma unroll
  for (int j = 0; j < 2; ++j) {
    int e = tid + j * 512;
    ra[j] = Ab[(size_t)(r0 + (e >> 3)) * ADc + (e & 7)];
    rb[j] = Bb[(size_t)(c0 + (e >> 3)) * ADc + (e & 7)];
  }
  #pragma unroll
  for (int j = 0; j < 2; ++j) {
    int e = tid + j * 512;
    As[0][e & 7][e >> 3] = ra[j];
    Bs[0][e & 7][e >> 3] = rb[j];
  }
  __syncthreads();
  for (int s = 0; s < 32; ++s) {
    const int cur = s & 1;
    if (s + 1 < 32) {
      const int k0 = (s + 1) << 3;
      #pragma unroll
      for (int j = 0; j < 2; ++j) {
        int e = tid + j * 512;
        ra[j] = Ab[(size_t)(r0 + (e >> 3)) * ADc + k0 + (e & 7)];
        rb[j] = Bb[(size_t)(c0 + (e >> 3)) * ADc + k0 + (e & 7)];
      }
    }
    #pragma unroll
    for (int kk = 0; kk < 8; ++kk) {
      float4 a0 = *(const float4*)&As[cur][kk][ty * 4];
      float4 a1 = *(const float4*)&As[cur][kk][64 + ty * 4];
      float2 w0 = *(const float2*)&Bs[cur][kk][tx * 2];
      float2 w1 = *(const float2*)&Bs[cur][kk][64 + tx * 2];
      float a[8] = {a0.x, a0.y, a0.z, a0.w, a1.x, a1.y, a1.z, a1.w};
      float w[4] = {w0.x, w0.y, w1.x, w1.y};
      #pragma unroll
      for (int i = 0; i < 8; ++i)
        #pragma unroll
        for (int j = 0; j < 4; ++j)
          acc[i][j] = fmaf(a[i], w[j], acc[i][j]);
    }
    if (s + 1 < 32) {
      #pragma unroll
      for (int j = 0; j < 2; ++j) {
        int e = tid + j * 512;
        As[cur ^ 1][e & 7][e >> 3] = ra[j];
        Bs[cur ^ 1][e & 7][e >> 3] = rb[j];
      }
    }
    __syncthreads();
  }
  #pragma unroll
  for (int i = 0; i < 8; ++i) {
    int r = r0 + g128row(i, ty);
    #pragma unroll
    for (int j = 0; j < 4; ++j)
      Cb[(size_t)r * Mmm + c0 + g128col(j, tx)] = acc[i][j] * inv_tau;
  }
}

// ---------------------------------------------------------------------------
// Shared 512-thread 64x64 dbuf GEMM core (K=256 small-C GEMMs).
// ---------------------------------------------------------------------------
__device__ __forceinline__ void g512core(
    const float* __restrict__ A, int lda, const float* __restrict__ W, int ldw,
    int kbeg, int kend, int r0, int c0, int tid,
    float As[2][16][68], float Ws[2][16][68], float acc[2][4])
{
  const int tx = tid & 15, ty = tid >> 4;
  float ra[2], rb[2];
  #pragma unroll
  for (int j = 0; j < 2; ++j) {
    int e = tid + j * 512;
    ra[j] = A[(size_t)(r0 + (e >> 4)) * lda + kbeg + (e & 15)];
    rb[j] = W[(size_t)(kbeg + (e >> 6)) * ldw + c0 + (e & 63)];
  }
  #pragma unroll
  for (int j = 0; j < 2; ++j) {
    int e = tid + j * 512;
    As[0][e & 15][e >> 4] = ra[j];
    Ws[0][e >> 6][e & 63] = rb[j];
  }
  __syncthreads();

  const int nstep = (kend - kbeg) >> 4;
  for (int s = 0; s < nstep; ++s) {
    const int cur = s & 1;
    if (s + 1 < nstep) {
      const int k0 = kbeg + ((s + 1) << 4);
      #pragma unroll
      for (int j = 0; j < 2; ++j) {
        int e = tid + j * 512;
        ra[j] = A[(size_t)(r0 + (e >> 4)) * lda + k0 + (e & 15)];
        rb[j] = W[(size_t)(k0 + (e >> 6)) * ldw + c0 + (e & 63)];
      }
    }
    #pragma unroll
    for (int kk = 0; kk < 16; ++kk) {
      float2 av = *(const float2*)&As[cur][kk][ty * 2];
      float4 wv = *(const float4*)&Ws[cur][kk][tx * 4];
      float a[2] = {av.x, av.y};
      float w[4] = {wv.x, wv.y, wv.z, wv.w};
      #pragma unroll
      for (int i = 0; i < 2; ++i)
        #pragma unroll
        for (int j = 0; j < 4; ++j)
          acc[i][j] = fmaf(a[i], w[j], acc[i][j]);
    }
    if (s + 1 < nstep) {
      #pragma unroll
      for (int j = 0; j < 2; ++j) {
        int e = tid + j * 512;
        As[cur ^ 1][e & 15][e >> 4] = ra[j];
        Ws[cur ^ 1][e >> 6][e & 63] = rb[j];
      }
    }
    __syncthreads();
  }
}

// Full GEMM with bias/addsrc epilogue (out-proj).
__global__ __launch_bounds__(512) void gemm512_k(
    const float* __restrict__ A, const float* __restrict__ W, const float* __restrict__ bias,
    const float* __restrict__ addsrc, float* __restrict__ C,
    int K, int Cc, int act)
{
  __shared__ __align__(16) float As[2][16][68];
  __shared__ __align__(16) float Ws[2][16][68];
  const int tid = threadIdx.x;
  const int tx = tid & 15, ty = tid >> 4;
  const int r0 = blockIdx.y * 64, c0 = blockIdx.x * 64;
  float acc[2][4] = {};
  g512core(A, K, W, Cc, 0, K, r0, c0, tid, As, Ws, acc);
  #pragma unroll
  for (int i = 0; i < 2; ++i) {
    int r = r0 + ty * 2 + i;
    #pragma unroll
    for (int j = 0; j < 4; ++j) {
      int c = c0 + tx * 4 + j;
      float v = acc[i][j] + bias[c];
      if (addsrc) v += addsrc[(size_t)r * Cc + c];
      if (act == 1) v = 0.5f * v * (1.f + erff(v * 0.70710678118654752f));
      C[(size_t)r * Cc + c] = v;
    }
  }
}

// q + kv GEMMs in one launch: z=0 -> q; z=1,2 -> kv halves.
__global__ __launch_bounds__(512) void qkv_k(
    const float* __restrict__ xq, const float* __restrict__ qw, const float* __restrict__ qb,
    float* __restrict__ qout,
    const float* __restrict__ xc, const float* __restrict__ kvw, const float* __restrict__ kvb,
    float* __restrict__ kvout)
{
  __shared__ __align__(16) float As[2][16][68];
  __shared__ __align__(16) float Ws[2][16][68];
  const int tid = threadIdx.x;
  const int tx = tid & 15, ty = tid >> 4;
  const int z = blockIdx.z;
  const float* A = (z == 0) ? xq : xc;
  const float* W = (z == 0) ? qw : kvw;
  const float* bias = (z == 0) ? qb : kvb;
  float* C = (z == 0) ? qout : kvout;
  const int ldw = (z == 0) ? 256 : 512;
  const int coff = (z == 0) ? 0 : (z - 1) * 256;
  const int r0 = blockIdx.y * 64, c0 = blockIdx.x * 64 + coff;
  float acc[2][4] = {};
  g512core(A, 256, W, ldw, 0, 256, r0, c0, tid, As, Ws, acc);
  #pragma unroll
  for (int i = 0; i < 2; ++i) {
    int r = r0 + ty * 2 + i;
    #pragma unroll
    for (int j = 0; j < 4; ++j) {
      int c = c0 + tx * 4 + j;
      C[(size_t)r * ldw + c] = acc[i][j] + bias[c];
    }
  }
}

// Paired correspondence GEMMs (z=0: src_corr, z=1: tgt_corr), K=Cc=256.
__global__ __launch_bounds__(512) void gemm_corr2_k(
    const float* __restrict__ A0, const float* __restrict__ W0, const float* __restrict__ b0,
    float* __restrict__ C0,
    const float* __restrict__ A1, const float* __restrict__ W1, const float* __restrict__ b1,
    float* __restrict__ C1)
{
  __shared__ __align__(16) float As[2][16][68];
  __shared__ __align__(16) float Ws[2][16][68];
  const int tid = threadIdx.x;
  const int tx = tid & 15, ty = tid >> 4;
  const int r0 = blockIdx.y * 64, c0 = blockIdx.x * 64;
  const float* A = blockIdx.z ? A1 : A0;
  const float* W = blockIdx.z ? W1 : W0;
  const float* bias = blockIdx.z ? b1 : b0;
  float* C = blockIdx.z ? C1 : C0;
  float acc[2][4] = {};
  g512core(A, 256, W, 256, 0, 256, r0, c0, tid, As, Ws, acc);
  #pragma unroll
  for (int i = 0; i < 2; ++i) {
    int r = r0 + ty * 2 + i;
    #pragma unroll
    for (int j = 0; j < 4; ++j) {
      int c = c0 + tx * 4 + j;
      C[(size_t)r * 256 + c] = acc[i][j] + bias[c];
    }
  }
}

// ---------------------------------------------------------------------------
// Fused split-K reduce + bias + LN1+ReLU (proj) + LN2 (pre-attn), x2 streams.
// ---------------------------------------------------------------------------
__device__ __forceinline__ void ln4f_body(
    const float* __restrict__ p, const float* __restrict__ bias,
    const float* __restrict__ g, const float* __restrict__ bb,
    float* __restrict__ oproj, float* __restrict__ oln,
    const float* __restrict__ n1g, const float* __restrict__ n1b, int row, int tid)
{
  size_t o = (size_t)row * 256 + tid;
  float x = p[o] + p[o + 1048576] + p[o + 2097152] + p[o + 3145728] + bias[tid];
  __shared__ float as_[4], as2_[4];
  const int wv = tid >> 6, ln = tid & 63;
  // LN1 + ReLU
  float s = x, s2 = x * x;
  #pragma unroll
  for (int off = 32; off > 0; off >>= 1) {
    s  += __shfl_xor(s, off, 64);
    s2 += __shfl_xor(s2, off, 64);
  }
  if (ln == 0) { as_[wv] = s; as2_[wv] = s2; }
  __syncthreads();
  s  = as_[0] + as_[1] + as_[2] + as_[3];
  s2 = as2_[0] + as2_[1] + as2_[2] + as2_[3];
  float mu = s * (1.f / 256.f);
  float var = fmaxf(s2 * (1.f / 256.f) - mu * mu, 0.f);
  float inv = 1.f / sqrtf(var + 1e-5f);
  float v = fmaxf((x - mu) * inv * g[tid] + bb[tid], 0.f);
  oproj[o] = v;
  // LN2 (n1 params) on v
  float t = v, t2 = v * v;
  #pragma unroll
  for (int off = 32; off > 0; off >>= 1) {
    t  += __shfl_xor(t, off, 64);
    t2 += __shfl_xor(t2, off, 64);
  }
  __syncthreads();   // everyone done reading as_ before overwrite
  if (ln == 0) { as_[wv] = t; as2_[wv] = t2; }
  __syncthreads();
  t  = as_[0] + as_[1] + as_[2] + as_[3];
  t2 = as2_[0] + as2_[1] + as2_[2] + as2_[3];
  float mu2 = t * (1.f / 256.f);
  float var2 = fmaxf(t2 * (1.f / 256.f) - mu2 * mu2, 0.f);
  float inv2 = 1.f / sqrtf(var2 + 1e-5f);
  oln[o] = (v - mu2) * inv2 * n1g[tid] + n1b[tid];
}

__global__ __launch_bounds__(256) void ln4x2f_k(
    const float* __restrict__ p0, const float* __restrict__ b0,
    const float* __restrict__ g0, const float* __restrict__ bb0,
    float* __restrict__ o0, float* __restrict__ q0,
    const float* __restrict__ p1, const float* __restrict__ b1,
    const float* __restrict__ g1, const float* __restrict__ bb1,
    float* __restrict__ o1, float* __restrict__ q1,
    const float* __restrict__ n1g, const float* __restrict__ n1b)
{
  const int row = blockIdx.x;
  if (row < Bn * Nn) ln4f_body(p0, b0, g0, bb0, o0, q0, n1g, n1b, row, threadIdx.x);
  else               ln4f_body(p1, b1, g1, bb1, o1, q1, n1g, n1b, row - Bn * Nn, threadIdx.x);
}

// Split-K reduce + bias + residual accumulate (for f2): out += sum(p) + bias.
__global__ __launch_bounds__(256) void red4_k(
    const float* __restrict__ p, const float* __restrict__ bias, float* __restrict__ out)
{
  size_t i = (size_t)blockIdx.x * 256 + threadIdx.x;
  out[i] += p[i] + p[i + 1048576] + p[i + 2097152] + p[i + 3145728] + bias[threadIdx.x];
}

// Pack [kw|vw] (256x512) and [kb|vb] into contiguous buffers.
__global__ __launch_bounds__(256) void pack_kv_k(
    const float* __restrict__ kw, const float* __restrict__ kb,
    const float* __restrict__ vw, const float* __restrict__ vb,
    float* __restrict__ kvw, float* __restrict__ kvb)
{
  int i = blockIdx.x * 256 + threadIdx.x;
  if (i < 256 * 512) {
    int r = i >> 9, c = i & 511;
    kvw[i] = (c < 256) ? kw[r * 256 + c] : vw[r * 256 + (c - 256)];
  } else if (i < 256 * 512 + 512) {
    int c = i - 256 * 512;
    kvb[c] = (c < 256) ? kb[c] : vb[c - 256];
  }
}

// ---------------------------------------------------------------------------
// Fast LayerNorm for Cc=256 (pre-FFN h).
// ---------------------------------------------------------------------------
__global__ __launch_bounds__(256) void ln2_k(
    const float* __restrict__ in, const float* __restrict__ g, const float* __restrict__ bb,
    float* __restrict__ out, int relu)
{
  const int row = blockIdx.x;
  const int tid = threadIdx.x;
  float x = in[(size_t)row * 256 + tid];
  float s = x, s2 = x * x;
  #pragma unroll
  for (int off = 32; off > 0; off >>= 1) {
    s  += __shfl_xor(s, off, 64);
    s2 += __shfl_xor(s2, off, 64);
  }
  __shared__ float as_[4], as2_[4];
  const int wv = tid >> 6, ln = tid & 63;
  if (ln == 0) { as_[wv] = s; as2_[wv] = s2; }
  __syncthreads();
  s  = as_[0] + as_[1] + as_[2] + as_[3];
  s2 = as2_[0] + as2_[1] + as2_[2] + as2_[3];
  float mu = s * (1.f / 256.f);
  float var = fmaxf(s2 * (1.f / 256.f) - mu * mu, 0.f);
  float inv = 1.f / sqrtf(var + 1e-5f);
  float v = (x - mu) * inv * g[tid] + bb[tid];
  if (relu) v = fmaxf(v, 0.f);
  out[(size_t)row * 256 + tid] = v;
}

// ---------------------------------------------------------------------------
// Flash cross-attention (round-9 measured-best version).
// 256 threads, 32-row Q tiles, 2 rows x 4 cols/thread; float2 RBF table;
// register prefetch of K/V tiles; packed kv input (row stride 512).
// ---------------------------------------------------------------------------
__global__ __launch_bounds__(256) void fattn(
    const float* __restrict__ q, const float* __restrict__ kv,
    const float* __restrict__ src_pts, const float* __restrict__ tgt_pts,
    const float* __restrict__ rbfw, float* __restrict__ ctx)
{
  const int bh = blockIdx.x;
  const int b = bh >> 2, h = bh & 3;
  const int n0 = blockIdx.y * 32;
  const int tid = threadIdx.x;
  const int tx = tid & 15, ty = tid >> 4;
  const int lane = tid & 63, w = tid >> 6;
  const int mml = lane >> 4;
  const int dd  = lane & 15;

  __shared__ __align__(16) float Qs[64][36];
  __shared__ __align__(16) float Ks[64][68];
  __shared__ __align__(16) float Vs[64][68];
  __shared__ __align__(16) float Ps[32][68];
  __shared__ float spx[32], spy[32], spz[32];
  __shared__ float tpx[64], tpy[64], tpz[64];
  __shared__ float rw[16];
  __shared__ __align__(8) float2 Tb[2048];

  if (tid < 16) rw[tid] = rbfw[tid * Hc + h];
  #pragma unroll
  for (int c = 0; c < 8; ++c) {
    int n = c * 4 + mml;
    int d = w * 16 + dd;
    Qs[d][n] = q[((size_t)b * Nn + n0 + n) * ADc + h * 64 + d];
  }
  if (tid < 32) {
    spx[tid] = src_pts[((size_t)b * Nn + n0 + tid) * 3 + 0];
    spy[tid] = src_pts[((size_t)b * Nn + n0 + tid) * 3 + 1];
    spz[tid] = src_pts[((size_t)b * Nn + n0 + tid) * 3 + 2];
  }
  __syncthreads();  // rw visible for table build

  // Build per-head bias table (8 entries/thread, one-time).
  for (int i = tid; i < 2048; i += 256) {
    float di = (float)i * (1.0f / 512.0f);
    float s0 = 0.f, s1 = 0.f;
    #pragma unroll
    for (int r = 0; r < NRc; ++r) {
      float dq0 = di - STEPc * r;
      float dq1 = dq0 + (1.0f / 512.0f);
      s0 = fmaf(__expf(COEFFc * dq0 * dq0), rw[r], s0);
      s1 = fmaf(__expf(COEFFc * dq1 * dq1), rw[r], s1);
    }
    Tb[i] = make_float2(s0, s1 - s0);
  }

  float kreg[16], vreg[16];
  float tp0 = 0.f, tp1 = 0.f, tp2 = 0.f;
  {
    const size_t kb_ = ((size_t)b * Mmm) * 512 + h * 64;
    #pragma unroll
    for (int c = 0; c < 16; ++c) {
      kreg[c] = kv[kb_ + (size_t)(c * 4 + mml) * 512 + w * 16 + dd];
      vreg[c] = kv[kb_ + (size_t)(c * 4 + w) * 512 + 256 + lane];
    }
    if (tid < 64) {
      tp0 = tgt_pts[((size_t)b * Mmm + tid) * 3 + 0];
      tp1 = tgt_pts[((size_t)b * Mmm + tid) * 3 + 1];
      tp2 = tgt_pts[((size_t)b * Mmm + tid) * 3 + 2];
    }
  }

  float O[2][4] = {};
  float mrun[2] = {-1e30f, -1e30f};
  float lrun[2] = {0.f, 0.f};

  for (int t = 0; t < Mmm / 64; ++t) {
    __syncthreads();   // previous tile fully consumed (also covers Tb/Qs at t=0)
    #pragma unroll
    for (int c = 0; c < 16; ++c) Ks[w * 16 + dd][c * 4 + mml] = kreg[c];
    #pragma unroll
    for (int c = 0; c < 16; ++c) Vs[c * 4 + w][lane] = vreg[c];
    if (tid < 64) { tpx[tid] = tp0; tpy[tid] = tp1; tpz[tid] = tp2; }
    if (t + 1 < Mmm / 64) {
      const size_t kb_ = ((size_t)b * Mmm + (t + 1) * 64) * 512 + h * 64;
      #pragma unroll
      for (int c = 0; c < 16; ++c) {
        kreg[c] = kv[kb_ + (size_t)(c * 4 + mml) * 512 + w * 16 + dd];
        vreg[c] = kv[kb_ + (size_t)(c * 4 + w) * 512 + 256 + lane];
      }
      if (tid < 64) {
        size_t tb_ = ((size_t)b * Mmm + (t + 1) * 64 + tid) * 3;
        tp0 = tgt_pts[tb_ + 0];
        tp1 = tgt_pts[tb_ + 1];
        tp2 = tgt_pts[tb_ + 2];
      }
    }
    __syncthreads();

    // QK^T
    float S[2][4] = {};
    #pragma unroll
    for (int d = 0; d < 64; ++d) {
      float2 qv = *(const float2*)&Qs[d][ty * 2];
      float4 kv4 = *(const float4*)&Ks[d][tx * 4];
      float kwv[4] = {kv4.x, kv4.y, kv4.z, kv4.w};
      #pragma unroll
      for (int j = 0; j < 4; ++j) {
        S[0][j] = fmaf(qv.x, kwv[j], S[0][j]);
        S[1][j] = fmaf(qv.y, kwv[j], S[1][j]);
      }
    }

    // geo bias via float2 table + online softmax
    #pragma unroll
    for (int i = 0; i < 2; ++i) {
      int n = ty * 2 + i;
      float s0 = spx[n], s1 = spy[n], s2 = spz[n];
      float sq = s0 * s0 + s1 * s1 + s2 * s2;
      float rmx = -1e30f;
      #pragma unroll
      for (int j = 0; j < 4; ++j) {
        int mj = tx * 4 + j;
        float t0 = tpx[mj], t1 = tpy[mj], t2 = tpz[mj];
        float d2 = sq + t0 * t0 + t1 * t1 + t2 * t2 - 2.f * (s0 * t0 + s1 * t1 + s2 * t2);
        float dist = sqrtf(fmaxf(d2, 0.f));
        float fidx = fminf(dist * 512.0f, 2047.0f);
        int i0 = (int)fidx;
        float frac = fidx - (float)i0;
        float2 tb = Tb[i0];
        float bias = fmaf(tb.y, frac, tb.x);
        float lv = S[i][j] * SCALEc + bias;
        S[i][j] = lv;
        rmx = fmaxf(rmx, lv);
      }
      #pragma unroll
      for (int off = 1; off < 16; off <<= 1)
        rmx = fmaxf(rmx, __shfl_xor(rmx, off, 64));
      float mn = fmaxf(mrun[i], rmx);
      float alpha = __expf(mrun[i] - mn);
      mrun[i] = mn;
      float p0 = __expf(S[i][0] - mn);
      float p1 = __expf(S[i][1] - mn);
      float p2 = __expf(S[i][2] - mn);
      float p3 = __expf(S[i][3] - mn);
      *(float4*)&Ps[n][tx * 4] = make_float4(p0, p1, p2, p3);
      float rs = p0 + p1 + p2 + p3;
      #pragma unroll
      for (int off = 1; off < 16; off <<= 1)
        rs += __shfl_xor(rs, off, 64);
      lrun[i] = lrun[i] * alpha + rs;
      O[i][0] *= alpha; O[i][1] *= alpha; O[i][2] *= alpha; O[i][3] *= alpha;
    }
    // Ps rows 2ty,2ty+1 are written+read by this wave only: no barrier.

    // PV
    #pragma unroll
    for (int m = 0; m < 64; ++m) {
      float4 vv = *(const float4*)&Vs[m][tx * 4];
      float vwv[4] = {vv.x, vv.y, vv.z, vv.w};
      float p0 = Ps[ty * 2][m];
      float p1 = Ps[ty * 2 + 1][m];
      #pragma unroll
      for (int j = 0; j < 4; ++j) {
        O[0][j] = fmaf(p0, vwv[j], O[0][j]);
        O[1][j] = fmaf(p1, vwv[j], O[1][j]);
      }
    }
  }

  #pragma unroll
  for (int i = 0; i < 2; ++i) {
    int n = n0 + ty * 2 + i;
    float invl = 1.f / lrun[i];
    size_t base = ((size_t)b * Nn + n) * ADc + h * 64 + tx * 4;
    ctx[base + 0] = O[i][0] * invl;
    ctx[base + 1] = O[i][1] * invl;
    ctx[base + 2] = O[i][2] * invl;
    ctx[base + 3] = O[i][3] * invl;
  }
}

// ---------------------------------------------------------------------------
// Sinkhorn, offset form: logS is READ-ONLY after the NT GEMM.
//   Rn = rowLSE(L0 - Cm); Cm = colLSE(L0 - Rn); (3x); S = exp(L0 - Rn - Cm)
// ---------------------------------------------------------------------------
__global__ __launch_bounds__(256) void row_lse3_k(
    const float* __restrict__ logS, const float* __restrict__ Cm, float* __restrict__ Rn)
{
  const int tid = threadIdx.x;
  const int bn = blockIdx.x;
  const int b = bn >> 10;
  const float* row = logS + (size_t)bn * Mmm;
  float4 v4 = *(const float4*)&row[tid * 4];
  if (Cm) {
    const float4 c4 = *(const float4*)&Cm[(size_t)b * Mmm + tid * 4];
    v4.x -= c4.x; v4.y -= c4.y; v4.z -= c4.z; v4.w -= c4.w;
  }
  float mx = fmaxf(fmaxf(v4.x, v4.y), fmaxf(v4.z, v4.w));
  float sm = __expf(v4.x - mx) + __expf(v4.y - mx) + __expf(v4.z - mx) + __expf(v4.w - mx);
  #pragma unroll
  for (int off = 32; off > 0; off >>= 1) {
    float mo = __shfl_xor(mx, off, 64);
    float so = __shfl_xor(sm, off, 64);
    float mn = fmaxf(mx, mo);
    sm = sm * __expf(mx - mn) + so * __expf(mo - mn);
    mx = mn;
  }
  __shared__ float wm[4], wsum[4];
  const int wv = tid >> 6, ln = tid & 63;
  if (ln == 0) { wm[wv] = mx; wsum[wv] = sm; }
  __syncthreads();
  if (tid == 0) {
    float m0 = fmaxf(fmaxf(wm[0], wm[1]), fmaxf(wm[2], wm[3]));
    float stot = wsum[0] * __expf(wm[0] - m0) + wsum[1] * __expf(wm[1] - m0)
               + wsum[2] * __expf(wm[2] - m0) + wsum[3] * __expf(wm[3] - m0);
    Rn[bn] = m0 + __logf(stot);
  }
}

__global__ __launch_bounds__(256) void col_part2_k(
    const float* __restrict__ logS, const float* __restrict__ Rn,
    float* __restrict__ pmax, float* __restrict__ psum)
{
  const int b = blockIdx.z, sp = blockIdx.y;
  const int m = blockIdx.x * 256 + threadIdx.x;
  const int RPS = Nn / NSPLIT;
  const float* base = logS + ((size_t)b * Nn + sp * RPS) * Mmm + m;
  const float* rn = Rn + (size_t)b * Nn + sp * RPS;
  float mx = -1e30f, sm = 0.f;
  for (int i = 0; i < RPS; ++i) {
    float v = base[(size_t)i * Mmm] - rn[i];
    if (v > mx) { sm = sm * __expf(mx - v) + 1.f; mx = v; }
    else sm += __expf(v - mx);
  }
  size_t o = ((size_t)b * NSPLIT + sp) * Mmm + m;
  pmax[o] = mx; psum[o] = sm;
}

__global__ __launch_bounds__(256) void col_comb_k(
    const float* __restrict__ pmax, const float* __restrict__ psum, float* __restrict__ colLse)
{
  const int b = blockIdx.y;
  const int m = blockIdx.x * 256 + threadIdx.x;
  float mx = -1e30f;
  for (int s = 0; s < NSPLIT; ++s) mx = fmaxf(mx, pmax[((size_t)b * NSPLIT + s) * Mmm + m]);
  float sm = 0.f;
  for (int s = 0; s < NSPLIT; ++s) {
    size_t o = ((size_t)b * NSPLIT + s) * Mmm + m;
    sm += psum[o] * __expf(pmax[o] - mx);
  }
  colLse[(size_t)b * Mmm + m] = mx + __logf(sm);
}

__global__ __launch_bounds__(256) void finalize2_k(
    const float* __restrict__ logS, const float* __restrict__ Rn, const float* __restrict__ Cm,
    const float* __restrict__ tgt_pts, float* __restrict__ outS, float* __restrict__ outConf,
    float* __restrict__ conf, float* __restrict__ tcp)
{
  const int tid = threadIdx.x;
  const int bn = blockIdx.x;
  const int b = bn >> 10;
  const float* row = logS + (size_t)bn * Mmm;
  const float rsub = Rn[bn];
  const float* cl = Cm + (size_t)b * Mmm;
  const float* tp = tgt_pts + (size_t)b * Mmm * 3;
  __shared__ float red[256];
  float mx = -1e30f, s0 = 0.f, s1 = 0.f, s2 = 0.f;
  for (int m = tid; m < Mmm; m += 256) {
    float sv = __expf(row[m] - rsub - cl[m]);
    outS[(size_t)bn * Mmm + m] = sv;
    mx = fmaxf(mx, sv);
    s0 = fmaf(sv, tp[m * 3 + 0], s0);
    s1 = fmaf(sv, tp[m * 3 + 1], s1);
    s2 = fmaf(sv, tp[m * 3 + 2], s2);
  }
  float rmx, r0, r1, r2;
  BLK_REDUCE_F(fmaxf, mx, rmx);
  BLK_REDUCE_F(addf, s0, r0);
  BLK_REDUCE_F(addf, s1, r1);
  BLK_REDUCE_F(addf, s2, r2);
  if (tid == 0) {
    conf[bn] = rmx;
    outConf[bn] = rmx;
    tcp[(size_t)bn * 3 + 0] = r0;
    tcp[(size_t)bn * 3 + 1] = r1;
    tcp[(size_t)bn * 3 + 2] = r2;
  }
}

// ---------------------------------------------------------------------------
// Kabsch: per-batch weighted sums + in-kernel SVD (thread 0). ONE launch.
// ---------------------------------------------------------------------------
__device__ __forceinline__ double trip(const double a[3], const double b[3], const double c[3]) {
  return a[0] * (b[1] * c[2] - b[2] * c[1])
       - a[1] * (b[0] * c[2] - b[2] * c[0])
       + a[2] * (b[0] * c[1] - b[1] * c[0]);
}

__device__ void kabsch_svd_dev(const double A[3][3], const double cs[3], const double ct[3],
                               int b, float* __restrict__ outR, float* __restrict__ outT)
{
  double Km[3][3];
  for (int i = 0; i < 3; ++i)
    for (int j = 0; j < 3; ++j)
      Km[i][j] = A[0][i] * A[0][j] + A[1][i] * A[1][j] + A[2][i] * A[2][j];
  double V[3][3] = {{1, 0, 0}, {0, 1, 0}, {0, 0, 1}};
  const int PP[3] = {0, 0, 1}, QQ[3] = {1, 2, 2};
  for (int sweep = 0; sweep < 30; ++sweep) {
    for (int pi = 0; pi < 3; ++pi) {
      int p = PP[pi], qd = QQ[pi];
      double apq = Km[p][qd];
      if (fabs(apq) < 1e-300) continue;
      double theta = (Km[qd][qd] - Km[p][p]) / (2.0 * apq);
      double tt = (theta >= 0 ? 1.0 : -1.0) / (fabs(theta) + sqrt(theta * theta + 1.0));
      double cc = 1.0 / sqrt(tt * tt + 1.0), ss = tt * cc;
      for (int r = 0; r < 3; ++r) {
        double kp = Km[r][p], kq = Km[r][qd];
        Km[r][p] = cc * kp - ss * kq; Km[r][qd] = ss * kp + cc * kq;
      }
      for (int c = 0; c < 3; ++c) {
        double kp = Km[p][c], kq = Km[qd][c];
        Km[p][c] = cc * kp - ss * kq; Km[qd][c] = ss * kp + cc * kq;
      }
      for (int r = 0; r < 3; ++r) {
        double vp = V[r][p], vq = V[r][qd];
        V[r][p] = cc * vp - ss * vq; V[r][qd] = ss * vp + cc * vq;
      }
    }
  }
  double lam[3] = {Km[0][0], Km[1][1], Km[2][2]};
  int i0 = 0, i1 = 1, i2 = 2, tsw;
  if (lam[i0] < lam[i1]) { tsw = i0; i0 = i1; i1 = tsw; }
  if (lam[i0] < lam[i2]) { tsw = i0; i0 = i2; i2 = tsw; }
  if (lam[i1] < lam[i2]) { tsw = i1; i1 = i2; i2 = tsw; }
  double vv[3][3];
  for (int r = 0; r < 3; ++r) { vv[0][r] = V[r][i0]; vv[1][r] = V[r][i1]; vv[2][r] = V[r][i2]; }
  double sg[3] = { sqrt(fmax(lam[i0], 0.0)), sqrt(fmax(lam[i1], 0.0)), sqrt(fmax(lam[i2], 0.0)) };

  double uu[3][3];
  double eps = 1e-12 * (sg[0] > 0 ? sg[0] : 1.0);
  if (sg[0] > eps) {
    for (int r = 0; r < 3; ++r)
      uu[0][r] = (A[r][0] * vv[0][0] + A[r][1] * vv[0][1] + A[r][2] * vv[0][2]) / sg[0];
    double n = sqrt(uu[0][0]*uu[0][0] + uu[0][1]*uu[0][1] + uu[0][2]*uu[0][2]);
    if (n > 1e-14) { uu[0][0]/=n; uu[0][1]/=n; uu[0][2]/=n; }
  } else { uu[0][0]=1; uu[0][1]=0; uu[0][2]=0; }
  if (sg[1] > eps) {
    for (int r = 0; r < 3; ++r)
      uu[1][r] = (A[r][0] * vv[1][0] + A[r][1] * vv[1][1] + A[r][2] * vv[1][2]) / sg[1];
  } else {
    int ax = (fabs(uu[0][0]) <= fabs(uu[0][1]) && fabs(uu[0][0]) <= fabs(uu[0][2])) ? 0
           : (fabs(uu[0][1]) <= fabs(uu[0][2]) ? 1 : 2);
    uu[1][0] = uu[1][1] = uu[1][2] = 0.0; uu[1][ax] = 1.0;
  }
  {
    double pr = uu[0][0]*uu[1][0] + uu[0][1]*uu[1][1] + uu[0][2]*uu[1][2];
    for (int r = 0; r < 3; ++r) uu[1][r] -= pr * uu[0][r];
    double n = sqrt(uu[1][0]*uu[1][0] + uu[1][1]*uu[1][1] + uu[1][2]*uu[1][2]);
    if (n > 1e-14) { uu[1][0]/=n; uu[1][1]/=n; uu[1][2]/=n; }
  }
  if (sg[2] > eps) {
    for (int r = 0; r < 3; ++r)
      uu[2][r] = (A[r][0] * vv[2][0] + A[r][1] * vv[2][1] + A[r][2] * vv[2][2]) / sg[2];
    double p0 = uu[0][0]*uu[2][0] + uu[0][1]*uu[2][1] + uu[0][2]*uu[2][2];
    double p1 = uu[1][0]*uu[2][0] + uu[1][1]*uu[2][1] + uu[1][2]*uu[2][2];
    for (int r = 0; r < 3; ++r) uu[2][r] -= p0 * uu[0][r] + p1 * uu[1][r];
    double n = sqrt(uu[2][0]*uu[2][0] + uu[2][1]*uu[2][1] + uu[2][2]*uu[2][2]);
    if (n > 1e-14) { uu[2][0]/=n; uu[2][1]/=n; uu[2][2]/=n; }
    else {
      uu[2][0] = uu[0][1]*uu[1][2] - uu[0][2]*uu[1][1];
      uu[2][1] = uu[0][2]*uu[1][0] - uu[0][0]*uu[1][2];
      uu[2][2] = uu[0][0]*uu[1][1] - uu[0][1]*uu[1][0];
    }
  } else {
    uu[2][0] = uu[0][1]*uu[1][2] - uu[0][2]*uu[1][1];
    uu[2][1] = uu[0][2]*uu[1][0] - uu[0][0]*uu[1][2];
    uu[2][2] = uu[0][0]*uu[1][1] - uu[0][1]*uu[1][0];
  }

  double detU = trip(uu[0], uu[1], uu[2]);
  double detV = trip(vv[0], vv[1], vv[2]);
  double d = (detU * detV < 0.0) ? -1.0 : 1.0;

  double R[3][3];
  for (int i = 0; i < 3; ++i)
    for (int j = 0; j < 3; ++j)
      R[i][j] = vv[0][i] * uu[0][j] + vv[1][i] * uu[1][j] + d * vv[2][i] * uu[2][j];
  for (int i = 0; i < 3; ++i) {
    double t = ct[i] - (R[i][0] * cs[0] + R[i][1] * cs[1] + R[i][2] * cs[2]);
    outT[(size_t)b * 3 + i] = (float)t;
    for (int j = 0; j < 3; ++j)
      outR[(size_t)b * 9 + i * 3 + j] = (float)R[i][j];
  }
}

__global__ __launch_bounds__(256) void kabsch_k(
    const float* __restrict__ conf, const float* __restrict__ src_pts,
    const float* __restrict__ tcp, float* __restrict__ outR, float* __restrict__ outT)
{
  const int b = blockIdx.x;
  const int tid = threadIdx.x;
  __shared__ double redd[256];
  __shared__ double sh[6];
  __shared__ double shk[9];
  const float* cb = conf + (size_t)b * Nn;
  const float* sb = src_pts + (size_t)b * Nn * 3;
  const float* tb = tcp + (size_t)b * Nn * 3;

  double a = 0.0;
  for (int n = tid; n < Nn; n += 256) a += (double)cb[n];
  double wsum; BLK_REDUCE_D(addd, a, wsum);
  double inv = 1.0 / (wsum + 1e-8);

  double c0 = 0, c1 = 0, c2 = 0, t0 = 0, t1 = 0, t2 = 0;
  for (int n = tid; n < Nn; n += 256) {
    double wn = (double)cb[n] * inv;
    c0 += wn * (double)sb[n * 3 + 0];
    c1 += wn * (double)sb[n * 3 + 1];
    c2 += wn * (double)sb[n * 3 + 2];
    t0 += wn * (double)tb[n * 3 + 0];
    t1 += wn * (double)tb[n * 3 + 1];
    t2 += wn * (double)tb[n * 3 + 2];
  }
  double r;
  BLK_REDUCE_D(addd, c0, r); if (tid == 0) sh[0] = r; __syncthreads();
  BLK_REDUCE_D(addd, c1, r); if (tid == 0) sh[1] = r; __syncthreads();
  BLK_REDUCE_D(addd, c2, r); if (tid == 0) sh[2] = r; __syncthreads();
  BLK_REDUCE_D(addd, t0, r); if (tid == 0) sh[3] = r; __syncthreads();
  BLK_REDUCE_D(addd, t1, r); if (tid == 0) sh[4] = r; __syncthreads();
  BLK_REDUCE_D(addd, t2, r); if (tid == 0) sh[5] = r; __syncthreads();
  double cs[3] = {sh[0], sh[1], sh[2]};
  double ct[3] = {sh[3], sh[4], sh[5]};

  double hm[9] = {};
  for (int n = tid; n < Nn; n += 256) {
    double wn = (double)cb[n] * inv;
    double d0 = (double)sb[n * 3 + 0] - cs[0];
    double d1 = (double)sb[n * 3 + 1] - cs[1];
    double d2 = (double)sb[n * 3 + 2] - cs[2];
    double e0 = (double)tb[n * 3 + 0] - ct[0];
    double e1 = (double)tb[n * 3 + 1] - ct[1];
    double e2 = (double)tb[n * 3 + 2] - ct[2];
    hm[0] += wn * d0 * e0; hm[1] += wn * d0 * e1; hm[2] += wn * d0 * e2;
    hm[3] += wn * d1 * e0; hm[4] += wn * d1 * e1; hm[5] += wn * d1 * e2;
    hm[6] += wn * d2 * e0; hm[7] += wn * d2 * e1; hm[8] += wn * d2 * e2;
  }
  for (int i = 0; i < 9; ++i) {
    BLK_REDUCE_D(addd, hm[i], r);
    if (tid == 0) shk[i] = r;
    __syncthreads();
  }
  if (tid == 0) {
    double A[3][3];
    for (int i = 0; i < 3; ++i)
      for (int j = 0; j < 3; ++j) A[i][j] = shk[i * 3 + j];
    kabsch_svd_dev(A, cs, ct, b, outR, outT);
  }
}

// x.max over N: partials over 64-row chunks (grid (B,16))
__global__ __launch_bounds__(256) void xmax_part_k(const float* __restrict__ x, float* __restrict__ part)
{
  const int b = blockIdx.x, ch = blockIdx.y;
  const int d = threadIdx.x;
  float mx = -1e30f;
  const int n0 = ch * 64;
  for (int n = n0; n < n0 + 64; ++n)
    mx = fmaxf(mx, x[((size_t)b * Nn + n) * ADc + d]);
  part[((size_t)b * 16 + ch) * ADc + d] = mx;
}

// Fused pool head: combine partials -> proj (256->512) -> LN -> ReLU -> concat.
__global__ __launch_bounds__(256) void pool_k(
    const float* __restrict__ part, const float* __restrict__ gp_w, const float* __restrict__ gp_b,
    const float* __restrict__ gp_g, const float* __restrict__ gp_bb,
    const float* __restrict__ tgt_glob, float* __restrict__ outC)
{
  const int b = blockIdx.x;
  const int tid = threadIdx.x;
  __shared__ float xm[256];
  float mx = -1e30f;
  #pragma unroll
  for (int c = 0; c < 16; ++c)
    mx = fmaxf(mx, part[((size_t)b * 16 + c) * 256 + tid]);
  xm[tid] = mx;
  __syncthreads();

  float acc0 = gp_b[tid], acc1 = gp_b[tid + 256];
  for (int k = 0; k < 256; ++k) {
    float xv = xm[k];
    acc0 = fmaf(xv, gp_w[(size_t)k * 512 + tid], acc0);
    acc1 = fmaf(xv, gp_w[(size_t)k * 512 + 256 + tid], acc1);
  }
  // LN over 512
  float s = acc0 + acc1, s2 = acc0 * acc0 + acc1 * acc1;
  #pragma unroll
  for (int off = 32; off > 0; off >>= 1) {
    s  += __shfl_xor(s, off, 64);
    s2 += __shfl_xor(s2, off, 64);
  }
  __shared__ float aw[4], aw2[4];
  const int wv = tid >> 6, ln = tid & 63;
  if (ln == 0) { aw[wv] = s; aw2[wv] = s2; }
  __syncthreads();
  s  = aw[0] + aw[1] + aw[2] + aw[3];
  s2 = aw2[0] + aw2[1] + aw2[2] + aw2[3];
  float mu = s * (1.f / 512.f);
  float var = fmaxf(s2 * (1.f / 512.f) - mu * mu, 0.f);
  float inv = 1.f / sqrtf(var + 1e-5f);
  float v0 = fmaxf((acc0 - mu) * inv * gp_g[tid] + gp_bb[tid], 0.f);
  float v1 = fmaxf((acc1 - mu) * inv * gp_g[tid + 256] + gp_bb[tid + 256], 0.f);
  size_t ob = (size_t)b * 1024;
  outC[ob + tid] = v0;
  outC[ob + 256 + tid] = v1;
  outC[ob + 512 + tid] = tgt_glob[(size_t)b * 512 + tid];
  outC[ob + 768 + tid] = tgt_glob[(size_t)b * 512 + 256 + tid];
}

// ---------------------------------------------------------------------------
extern "C" void kernel_launch(void* const* d_in, const int* in_sizes, int n_in,
                              void* d_out, int out_size, void* d_ws, size_t ws_size,
                              hipStream_t stream) {
  (void)in_sizes; (void)n_in; (void)out_size; (void)ws_size;
  const float* src_feats = (const float*)d_in[0];
  const float* tgt_feats = (const float*)d_in[1];
  const float* src_pts   = (const float*)d_in[2];
  const float* tgt_pts   = (const float*)d_in[3];
  const float* tgt_glob  = (const float*)d_in[4];
  const float* sfp_w = (const float*)d_in[5];  const float* sfp_b = (const float*)d_in[6];
  const float* sfp_g = (const float*)d_in[7];  const float* sfp_bb = (const float*)d_in[8];
  const float* tfp_w = (const float*)d_in[9];  const float* tfp_b = (const float*)d_in[10];
  const float* tfp_g = (const float*)d_in[11]; const float* tfp_bb = (const float*)d_in[12];
  const float* rbf_w = (const float*)d_in[13];
  const float* qw = (const float*)d_in[14]; const float* qb = (const float*)d_in[15];
  const float* kw = (const float*)d_in[16]; const float* kb = (const float*)d_in[17];
  const float* vw = (const float*)d_in[18]; const float* vb = (const float*)d_in[19];
  const float* ow = (const float*)d_in[20]; const float* ob = (const float*)d_in[21];
  const float* n1_g = (const float*)d_in[22]; const float* n1_b = (const float*)d_in[23];
  const float* f1_w = (const float*)d_in[24]; const float* f1_b = (const float*)d_in[25];
  const float* f2_w = (const float*)d_in[26]; const float* f2_b = (const float*)d_in[27];
  const float* n2_g = (const float*)d_in[28]; const float* n2_b = (const float*)d_in[29];
  const float* scp_w = (const float*)d_in[30]; const float* scp_b = (const float*)d_in[31];
  const float* tcp_w = (const float*)d_in[32]; const float* tcp_b = (const float*)d_in[33];
  const float* temp  = (const float*)d_in[34];
  const float* gp_w = (const float*)d_in[35]; const float* gp_b = (const float*)d_in[36];
  const float* gp_g = (const float*)d_in[37]; const float* gp_bb = (const float*)d_in[38];

  float* out = (float*)d_out;
  float* outR    = out;                    // (B,3,3)
  float* outT    = out + 36;               // (B,3)
  float* outC    = out + 48;               // (B,1024)
  float* outConf = out + 48 + 4096;        // (B,N)
  float* outS    = out + 48 + 4096 + 4096; // (B,N,M) -- split-K / tgt_corr scratch

  float* ws = (float*)d_ws;
  const size_t M1 = 1048576;
  float* A_   = ws + 0 * M1;
  float* B_   = ws + 1 * M1;
  float* C_   = ws + 2 * M1;
  float* D_   = ws + 3 * M1;   // kv packed output spans D..E (8MB)
  float* E_   = ws + 4 * M1;
  float* F_   = ws + 5 * M1;
  float* G_   = ws + 6 * M1;
  float* logS = ws + 0 * M1;     // slots 0..3
  float* hid  = ws + 1 * M1;     // slots 1..4
  float* tail = ws + 7 * M1;
  float* colLse = tail;                         // 4096
  float* pmax   = colLse + 4096;                // 131072 (also kvw pack)
  float* psum   = pmax + 131072;                // 131072 (also kvb pack)
  float* conf   = psum + 131072;                // 4096
  float* tcp    = conf + 4096;                  // 12288
  float* xmax   = tcp + 12288;                  // 1024 (layout keep)
  float* glraw  = xmax + 1024;                  // 2048 (layout keep)
  float* gl     = glraw + 2048;                 // 2048 (layout keep)
  double* kab   = (double*)(gl + 2048);         // 128 floats (layout keep)
  float* xpart  = (float*)(kab + 64);           // 16384 floats
  float* Rn     = xpart + 16384;                // 4096 (Sinkhorn row offsets)
  float* kvw    = pmax;                         // 131072 floats = 256x512
  float* kvb    = psum;                         // 512 floats

  const int BN = Bn * Nn;   // 4096

  // 0) pack [kw|vw] weights (dead Sinkhorn buffers; consumed before Sinkhorn)
  pack_kv_k<<<514, 256, 0, stream>>>(kw, kb, vw, vb, kvw, kvb);

  // 1) BOTH projections in one split-K launch; fused reduce+LN+ReLU+preLN
  proj2sk_k<<<dim3(2, 32, 8), 512, 0, stream>>>(src_feats, sfp_w, tgt_feats, tfp_w, outS, hid);
  ln4x2f_k<<<2 * BN, 256, 0, stream>>>(outS, sfp_b, sfp_g, sfp_bb, G_, A_,
                                       hid, tfp_b, tfp_g, tfp_bb, F_, B_,
                                       n1_g, n1_b);   // G=src_proj, A=xq, F=tgt_proj, B=xc

  // 2) q + kv in one launch
  qkv_k<<<dim3(4, 64, 3), 512, 0, stream>>>(A_, qw, qb, C_, B_, kvw, kvb, D_);

  // 3) flash attention, out-proj + residual
  fattn<<<dim3(Bn * Hc, Nn / 32), 256, 0, stream>>>(C_, D_, src_pts, tgt_pts, rbf_w, B_);  // ctx -> B
  gemm512_k<<<dim3(4, 64), 512, 0, stream>>>(B_, ow, ob, G_, G_, ADc, ADc, 0);

  // 4) FFN
  ln2_k<<<BN, 256, 0, stream>>>(G_, n2_g, n2_b, A_, 0);                       // h -> A
  gemm128_k<<<dim3(8, 32), 512, 0, stream>>>(A_, f1_w, f1_b, hid, ADc, 1024, 1);
  gemm128sk_k<<<dim3(2, 32, 4), 512, 0, stream>>>(hid, f2_w, outS);
  red4_k<<<BN, 256, 0, stream>>>(outS, f2_b, G_);                             // x += ffn

  // 5) correspondences (paired): src_corr -> E, tgt_corr -> outS
  gemm_corr2_k<<<dim3(4, 64, 2), 512, 0, stream>>>(G_, scp_w, scp_b, E_,
                                                   F_, tcp_w, tcp_b, outS);
  gemm128nt_k<<<dim3(8, 8, Bn), 512, 0, stream>>>(E_, outS, logS, temp);

  // 6) Sinkhorn (offset form, logS read-only) + finalize
  for (int it = 0; it < 3; ++it) {
    row_lse3_k<<<BN, 256, 0, stream>>>(logS, it == 0 ? nullptr : colLse, Rn);
    col_part2_k<<<dim3(Mmm / 256, NSPLIT, Bn), 256, 0, stream>>>(logS, Rn, pmax, psum);
    col_comb_k<<<dim3(Mmm / 256, Bn), 256, 0, stream>>>(pmax, psum, colLse);
  }
  finalize2_k<<<BN, 256, 0, stream>>>(logS, Rn, colLse, tgt_pts, outS, outConf, conf, tcp);

  // 7) Kabsch (reduce + SVD in one kernel)
  kabsch_k<<<Bn, 256, 0, stream>>>(conf, src_pts, tcp, outR, outT);

  // 8) global pooling head (G intact): partials + fused tail
  xmax_part_k<<<dim3(Bn, 16), 256, 0, stream>>>(G_, xpart);
  pool_k<<<Bn, 256, 0, stream>>>(xpart, gp_w, gp_b, gp_g, gp_bb, tgt_glob, outC);
}